// Round 1
// baseline (244.634 us; speedup 1.0000x reference)
//
#include <hip/hip_runtime.h>
#include <hip/hip_bf16.h>
#include <stdint.h>

#define B_ 4
#define C_ 256
#define N_ 4096
#define CR_ 32
#define LOG2E_F 1.44269504088896340736f

typedef __attribute__((ext_vector_type(8))) short bf16x8;
typedef __attribute__((ext_vector_type(4))) float f32x4;

__device__ __forceinline__ uint32_t cvt_pk_bf16(float lo, float hi) {
    uint32_t r;
    asm("v_cvt_pk_bf16_f32 %0, %1, %2" : "=v"(r) : "v"(lo), "v"(hi));
    return r;
}

__device__ __forceinline__ float fast_exp2(float x) {
#if __has_builtin(__builtin_amdgcn_exp2f)
    return __builtin_amdgcn_exp2f(x);
#else
    return exp2f(x);
#endif
}

// ---------------------------------------------------------------------------
// Projection kernel. grid (N/64, B), block 384 (6 waves).
// parts 0,1: f = Wv x + bv  -> q_t[b][n][cr] bf16, PRE-SCALED by log2(e)
// parts 2,3: g = Wk x + bk  -> k_t[b][n][cr] bf16
// parts 4,5: h = Wq x + bq  -> h_n[b][cr][n] bf16 (natural layout)
// ---------------------------------------------------------------------------
__global__ __launch_bounds__(384) void proj_kernel(
    const float* __restrict__ x,
    const float* __restrict__ Wv, const float* __restrict__ bv,
    const float* __restrict__ Wk, const float* __restrict__ bk,
    const float* __restrict__ Wq, const float* __restrict__ bq,
    __hip_bfloat16* __restrict__ q_t,
    __hip_bfloat16* __restrict__ k_t,
    __hip_bfloat16* __restrict__ h_n)
{
    const int tid  = threadIdx.x;
    const int lane = tid & 63;
    const int part = __builtin_amdgcn_readfirstlane(tid >> 6);
    const int b    = blockIdx.y;
    const int n0   = blockIdx.x * 64;

    if (part < 4) {
        // ---- transposed-output projections (f, g): one n per lane ----
        const int isF = ((part >> 1) == 0);
        const int cr0 = (part & 1) * 16;
        const float* __restrict__ W    = isF ? Wv : Wk;
        const float* __restrict__ bias = isF ? bv : bk;
        const int n = n0 + lane;
        float acc[16];
        #pragma unroll
        for (int k = 0; k < 16; ++k) acc[k] = bias[cr0 + k];
        const float* xcol = x + (size_t)b * C_ * N_ + n;
        for (int c = 0; c < C_; c += 4) {
            const float xv0 = xcol[(size_t)(c + 0) * N_];
            const float xv1 = xcol[(size_t)(c + 1) * N_];
            const float xv2 = xcol[(size_t)(c + 2) * N_];
            const float xv3 = xcol[(size_t)(c + 3) * N_];
            #pragma unroll
            for (int k = 0; k < 16; ++k) {
                const float4 w4 = *(const float4*)&W[(size_t)(cr0 + k) * C_ + c];
                acc[k] += w4.x * xv0 + w4.y * xv1 + w4.z * xv2 + w4.w * xv3;
            }
        }
        const float scale = isF ? LOG2E_F : 1.0f;
        uint32_t pk[8];
        #pragma unroll
        for (int r = 0; r < 8; ++r)
            pk[r] = cvt_pk_bf16(acc[2 * r] * scale, acc[2 * r + 1] * scale);
        __hip_bfloat16* dst = (isF ? q_t : k_t) + ((size_t)b * N_ + n) * CR_ + cr0;
        ((uint4*)dst)[0] = make_uint4(pk[0], pk[1], pk[2], pk[3]);
        ((uint4*)dst)[1] = make_uint4(pk[4], pk[5], pk[6], pk[7]);
    } else {
        // ---- natural-layout projection (h): one cr x 16 n per lane ----
        const int cr = (part & 1) * 16 + (lane >> 2);
        const int nb = n0 + (lane & 3) * 16;
        float acc[16];
        const float binit = bq[cr];
        #pragma unroll
        for (int k = 0; k < 16; ++k) acc[k] = binit;
        const float* wrow = Wq + (size_t)cr * C_;
        for (int c = 0; c < C_; ++c) {
            const float wv = wrow[c];
            const float* xr = x + ((size_t)b * C_ + c) * N_ + nb;
            const float4 x0 = *(const float4*)&xr[0];
            const float4 x1 = *(const float4*)&xr[4];
            const float4 x2 = *(const float4*)&xr[8];
            const float4 x3 = *(const float4*)&xr[12];
            acc[0]  += wv * x0.x; acc[1]  += wv * x0.y; acc[2]  += wv * x0.z; acc[3]  += wv * x0.w;
            acc[4]  += wv * x1.x; acc[5]  += wv * x1.y; acc[6]  += wv * x1.z; acc[7]  += wv * x1.w;
            acc[8]  += wv * x2.x; acc[9]  += wv * x2.y; acc[10] += wv * x2.z; acc[11] += wv * x2.w;
            acc[12] += wv * x3.x; acc[13] += wv * x3.y; acc[14] += wv * x3.z; acc[15] += wv * x3.w;
        }
        uint32_t pk[8];
        #pragma unroll
        for (int r = 0; r < 8; ++r)
            pk[r] = cvt_pk_bf16(acc[2 * r], acc[2 * r + 1]);
        __hip_bfloat16* dst = h_n + ((size_t)b * CR_ + cr) * N_ + nb;
        ((uint4*)dst)[0] = make_uint4(pk[0], pk[1], pk[2], pk[3]);
        ((uint4*)dst)[1] = make_uint4(pk[4], pk[5], pk[6], pk[7]);
    }
}

// ---------------------------------------------------------------------------
// Flash attention + fused output projection. grid (N/64, B), block 256 (4 waves).
// Wave w owns 16 query rows. j-tile = 64 (4 S-MFMAs, 4 PV-MFMAs per iter).
// S-tile t covers columns j = j0 + 4n + t (n = lane&15) so P pack is ds_write_b64
// and PV's k-index order equals natural j order.
// ---------------------------------------------------------------------------
__global__ __launch_bounds__(256) void flash_kernel(
    const __hip_bfloat16* __restrict__ q_t,
    const __hip_bfloat16* __restrict__ k_t,
    const __hip_bfloat16* __restrict__ h_n,
    const float* __restrict__ x,
    const float* __restrict__ Wo, const float* __restrict__ bo,
    const float* __restrict__ gamma_p,
    float* __restrict__ y)
{
    __shared__ __hip_bfloat16 p_lds[4][16][72];  // per-wave P tile, padded stride
    __shared__ float out_lds[32][65];            // [cr][i_local], padded

    const int tid  = threadIdx.x;
    const int lane = tid & 63;
    const int w    = tid >> 6;
    const int b    = blockIdx.y;
    const int i0   = blockIdx.x * 64;
    const int iw   = i0 + w * 16;

    const int m  = lane & 15;
    const int h4 = lane >> 4;  // 0..3

    // Q A-fragment: row = lane&15, k = 8*(lane>>4)+e  (contiguous in q_t)
    const bf16x8 qa = *(const bf16x8*)(q_t + ((size_t)b * N_ + iw + m) * CR_ + 8 * h4);

    f32x4 acc0 = {0.f, 0.f, 0.f, 0.f};
    f32x4 acc1 = {0.f, 0.f, 0.f, 0.f};
    float m_run[4] = {-INFINITY, -INFINITY, -INFINITY, -INFINITY};
    float l_part[4] = {0.f, 0.f, 0.f, 0.f};

    const __hip_bfloat16* kbase = k_t + (size_t)b * N_ * CR_;
    const __hip_bfloat16* hbase = h_n + (size_t)b * CR_ * N_;
    const f32x4 z = {0.f, 0.f, 0.f, 0.f};

    for (int j0 = 0; j0 < N_; j0 += 64) {
        // K B-fragments: tile t, col n=lane&15 -> row j0+4n+t, k = 8*h4+e
        bf16x8 kb[4];
        #pragma unroll
        for (int t = 0; t < 4; ++t)
            kb[t] = *(const bf16x8*)(kbase + (size_t)(j0 + 4 * m + t) * CR_ + 8 * h4);

        f32x4 s[4];
        #pragma unroll
        for (int t = 0; t < 4; ++t)
            s[t] = __builtin_amdgcn_mfma_f32_16x16x32_bf16(qa, kb[t], z, 0, 0, 0);

        // in-lane tile max per row r (rows i = 4*h4 + r)
        float mt[4];
        #pragma unroll
        for (int r = 0; r < 4; ++r)
            mt[r] = fmaxf(fmaxf(s[0][r], s[1][r]), fmaxf(s[2][r], s[3][r]));
        const float dmax = fmaxf(fmaxf(mt[0] - m_run[0], mt[1] - m_run[1]),
                                 fmaxf(mt[2] - m_run[2], mt[3] - m_run[3]));
        if (__any(dmax > 8.0f)) {
            // full 16-lane row-max reduce + rescale (rare after warmup)
            #pragma unroll
            for (int r = 0; r < 4; ++r) {
                float v = mt[r];
                v = fmaxf(v, __shfl_xor(v, 1));
                v = fmaxf(v, __shfl_xor(v, 2));
                v = fmaxf(v, __shfl_xor(v, 4));
                v = fmaxf(v, __shfl_xor(v, 8));
                const float mn = fmaxf(m_run[r], v);
                const float sc = fast_exp2(m_run[r] - mn);
                m_run[r] = mn;
                l_part[r] *= sc;
                acc0[r] *= sc;
                acc1[r] *= sc;
            }
        }

        // P = exp2(s - m), per-lane partial l, pack -> LDS (4 x ds_write_b64)
        #pragma unroll
        for (int r = 0; r < 4; ++r) {
            const float p0 = fast_exp2(s[0][r] - m_run[r]);
            const float p1 = fast_exp2(s[1][r] - m_run[r]);
            const float p2 = fast_exp2(s[2][r] - m_run[r]);
            const float p3 = fast_exp2(s[3][r] - m_run[r]);
            l_part[r] += (p0 + p1) + (p2 + p3);
            uint2 v;
            v.x = cvt_pk_bf16(p0, p1);
            v.y = cvt_pk_bf16(p2, p3);
            *(uint2*)&p_lds[w][4 * h4 + r][4 * m] = v;  // cols 4m..4m+3 = j_local
        }
        asm volatile("s_waitcnt lgkmcnt(0)" ::: "memory");
        __builtin_amdgcn_sched_barrier(0);

        // P A-fragments (row = lane&15, k = 8*h4+e), contiguous b128 reads
        const bf16x8 pa0 = *(const bf16x8*)&p_lds[w][m][8 * h4];
        const bf16x8 pa1 = *(const bf16x8*)&p_lds[w][m][32 + 8 * h4];

        // H B-fragments: col c = lane&15 (+16), k = j_local = q0 + 8*h4+e
        const __hip_bfloat16* hb_b = hbase + j0 + 8 * h4;
        const bf16x8 hb00 = *(const bf16x8*)(hb_b + (size_t)m * N_);
        const bf16x8 hb01 = *(const bf16x8*)(hb_b + (size_t)(16 + m) * N_);
        const bf16x8 hb10 = *(const bf16x8*)(hb_b + 32 + (size_t)m * N_);
        const bf16x8 hb11 = *(const bf16x8*)(hb_b + 32 + (size_t)(16 + m) * N_);

        acc0 = __builtin_amdgcn_mfma_f32_16x16x32_bf16(pa0, hb00, acc0, 0, 0, 0);
        acc0 = __builtin_amdgcn_mfma_f32_16x16x32_bf16(pa1, hb10, acc0, 0, 0, 0);
        acc1 = __builtin_amdgcn_mfma_f32_16x16x32_bf16(pa0, hb01, acc1, 0, 0, 0);
        acc1 = __builtin_amdgcn_mfma_f32_16x16x32_bf16(pa1, hb11, acc1, 0, 0, 0);
    }

    // final l reduce across the 16 lanes of each row, normalize, stash to LDS
    #pragma unroll
    for (int r = 0; r < 4; ++r) {
        float v = l_part[r];
        v += __shfl_xor(v, 1);
        v += __shfl_xor(v, 2);
        v += __shfl_xor(v, 4);
        v += __shfl_xor(v, 8);
        const float inv = 1.0f / v;
        const int il = w * 16 + 4 * h4 + r;
        out_lds[m][il]      = acc0[r] * inv;
        out_lds[16 + m][il] = acc1[r] * inv;
    }
    __syncthreads();

    // fused output projection: y = gamma * (Wo @ out + bo) + x
    const int il  = tid & 63;
    const int cog = __builtin_amdgcn_readfirstlane(tid >> 6);
    float vals[32];
    #pragma unroll
    for (int cr = 0; cr < 32; ++cr) vals[cr] = out_lds[cr][il];
    const float g = gamma_p[0];
    const float* xb = x + (size_t)b * C_ * N_ + i0 + il;
    float* yb = y + (size_t)b * C_ * N_ + i0 + il;
    for (int k = 0; k < 64; ++k) {
        const int co = cog * 64 + k;
        const float* wr = Wo + (size_t)co * CR_;
        float a = bo[co];
        #pragma unroll
        for (int cr = 0; cr < 32; ++cr) a += wr[cr] * vals[cr];
        yb[(size_t)co * N_] = g * a + xb[(size_t)co * N_];
    }
}

extern "C" void kernel_launch(void* const* d_in, const int* in_sizes, int n_in,
                              void* d_out, int out_size, void* d_ws, size_t ws_size,
                              hipStream_t stream) {
    (void)in_sizes; (void)n_in; (void)out_size; (void)ws_size;
    const float* x  = (const float*)d_in[0];
    const float* Wv = (const float*)d_in[1];
    const float* bv = (const float*)d_in[2];
    const float* Wk = (const float*)d_in[3];
    const float* bk = (const float*)d_in[4];
    const float* Wq = (const float*)d_in[5];
    const float* bq = (const float*)d_in[6];
    const float* Wo = (const float*)d_in[7];
    const float* bo = (const float*)d_in[8];
    const float* gm = (const float*)d_in[9];
    float* y = (float*)d_out;

    __hip_bfloat16* q_t = (__hip_bfloat16*)d_ws;                 // f * log2e, [B][N][CR]
    __hip_bfloat16* k_t = q_t + (size_t)B_ * N_ * CR_;           // g, [B][N][CR]
    __hip_bfloat16* h_n = k_t + (size_t)B_ * N_ * CR_;           // h, [B][CR][N]

    proj_kernel<<<dim3(N_ / 64, B_), 384, 0, stream>>>(x, Wv, bv, Wk, bk, Wq, bq,
                                                       q_t, k_t, h_n);
    flash_kernel<<<dim3(N_ / 64, B_), 256, 0, stream>>>(q_t, k_t, h_n, x, Wo, bo, gm, y);
}

// Round 2
// 197.128 us; speedup vs baseline: 1.2410x; 1.2410x over previous
//
#include <hip/hip_runtime.h>
#include <hip/hip_bf16.h>
#include <stdint.h>

#define B_ 4
#define C_ 256
#define N_ 4096
#define CR_ 32
#define JS_ 4                 // j-split factor
#define CHUNK_ (N_ / JS_)     // 1024 j's per chunk
#define NT_ (CHUNK_ / 64)     // 16 tiles per chunk
#define LOG2E_F 1.44269504088896340736f

typedef __attribute__((ext_vector_type(8))) short bf16x8;
typedef __attribute__((ext_vector_type(4))) float f32x4;

__device__ __forceinline__ uint32_t cvt_pk_bf16(float lo, float hi) {
    uint32_t r;
    asm("v_cvt_pk_bf16_f32 %0, %1, %2" : "=v"(r) : "v"(lo), "v"(hi));
    return r;
}

__device__ __forceinline__ float fast_exp2(float x) {
#if __has_builtin(__builtin_amdgcn_exp2f)
    return __builtin_amdgcn_exp2f(x);
#else
    return exp2f(x);
#endif
}

// ---------------------------------------------------------------------------
// Projection kernel. grid (N/64, B), block 512 (8 waves).
// Stage x[256][64] tile in LDS once (coalesced), then wave g computes channels
// 4g..4g+3 of ALL THREE projections from LDS with uniform (scalar) W loads.
//   f = Wv x + bv  -> q_t[b][n][cr] bf16, PRE-SCALED by log2(e)
//   g = Wk x + bk  -> k_t[b][n][cr] bf16
//   h = Wq x + bq  -> h_n[b][cr][n] bf16 (natural layout)
// ---------------------------------------------------------------------------
__global__ __launch_bounds__(512, 2) void proj_kernel(
    const float* __restrict__ x,
    const float* __restrict__ Wv, const float* __restrict__ bv,
    const float* __restrict__ Wk, const float* __restrict__ bk,
    const float* __restrict__ Wq, const float* __restrict__ bq,
    __hip_bfloat16* __restrict__ q_t,
    __hip_bfloat16* __restrict__ k_t,
    __hip_bfloat16* __restrict__ h_n)
{
    __shared__ float xs[C_][64];  // 64 KB

    const int tid = threadIdx.x;
    const int b   = blockIdx.y;
    const int n0  = blockIdx.x * 64;

    // ---- stage x tile (each thread 8 float4s, perfectly coalesced) ----
    #pragma unroll
    for (int k = 0; k < 8; ++k) {
        const int idx = tid + 512 * k;
        const int row = idx >> 4;
        const int c4  = (idx & 15) * 4;
        *(float4*)&xs[row][c4] =
            *(const float4*)&x[((size_t)b * C_ + row) * N_ + n0 + c4];
    }
    __syncthreads();

    const int lane = tid & 63;                                   // n within tile
    const int g    = __builtin_amdgcn_readfirstlane(tid >> 6);   // 0..7

    float af[4], ag[4], ah[4];
    #pragma unroll
    for (int k = 0; k < 4; ++k) {
        af[k] = bv[4 * g + k];
        ag[k] = bk[4 * g + k];
        ah[k] = bq[4 * g + k];
    }

    for (int c = 0; c < C_; c += 4) {
        const float xv0 = xs[c + 0][lane];
        const float xv1 = xs[c + 1][lane];
        const float xv2 = xs[c + 2][lane];
        const float xv3 = xs[c + 3][lane];
        #pragma unroll
        for (int k = 0; k < 4; ++k) {
            const float4 wv = *(const float4*)&Wv[(size_t)(4 * g + k) * C_ + c];
            af[k] += wv.x * xv0 + wv.y * xv1 + wv.z * xv2 + wv.w * xv3;
            const float4 wk = *(const float4*)&Wk[(size_t)(4 * g + k) * C_ + c];
            ag[k] += wk.x * xv0 + wk.y * xv1 + wk.z * xv2 + wk.w * xv3;
            const float4 wq = *(const float4*)&Wq[(size_t)(4 * g + k) * C_ + c];
            ah[k] += wq.x * xv0 + wq.y * xv1 + wq.z * xv2 + wq.w * xv3;
        }
    }

    // ---- stores ----
    const int n = n0 + lane;
    uint2 qv, kv;
    qv.x = cvt_pk_bf16(af[0] * LOG2E_F, af[1] * LOG2E_F);
    qv.y = cvt_pk_bf16(af[2] * LOG2E_F, af[3] * LOG2E_F);
    kv.x = cvt_pk_bf16(ag[0], ag[1]);
    kv.y = cvt_pk_bf16(ag[2], ag[3]);
    *(uint2*)&q_t[((size_t)b * N_ + n) * CR_ + 4 * g] = qv;
    *(uint2*)&k_t[((size_t)b * N_ + n) * CR_ + 4 * g] = kv;
    #pragma unroll
    for (int k = 0; k < 4; ++k)
        h_n[((size_t)b * CR_ + 4 * g + k) * N_ + n] = __float2bfloat16(ah[k]);
}

// ---------------------------------------------------------------------------
// Flash attention, j-split. grid (N/64, B, JS), block 256 (4 waves).
// Wave w owns 16 query rows; block handles j in [js*CHUNK, (js+1)*CHUNK).
// Double-buffered register prefetch of K/H fragments (no barriers, per-wave
// LDS P round-trip ordered by compiler alias analysis).
// Emits unnormalized partial acc + (m, l) per row to workspace.
// ---------------------------------------------------------------------------
__global__ __launch_bounds__(256, 4) void flash_kernel(
    const __hip_bfloat16* __restrict__ q_t,
    const __hip_bfloat16* __restrict__ k_t,
    const __hip_bfloat16* __restrict__ h_n,
    float* __restrict__ ws_acc,   // [B][JS][CR][N]
    float* __restrict__ ws_ml)    // [B][JS][2][N]
{
    __shared__ __hip_bfloat16 p_lds[4][16][72];  // per-wave P tile

    const int tid  = threadIdx.x;
    const int lane = tid & 63;
    const int w    = __builtin_amdgcn_readfirstlane(tid >> 6);
    const int b    = blockIdx.y;
    const int js   = blockIdx.z;
    const int i0   = blockIdx.x * 64;
    const int iw   = i0 + w * 16;

    const int m  = lane & 15;
    const int h4 = lane >> 4;  // 0..3

    const bf16x8 qa = *(const bf16x8*)(q_t + ((size_t)b * N_ + iw + m) * CR_ + 8 * h4);

    f32x4 acc0 = {0.f, 0.f, 0.f, 0.f};
    f32x4 acc1 = {0.f, 0.f, 0.f, 0.f};
    float m_run[4]  = {-INFINITY, -INFINITY, -INFINITY, -INFINITY};
    float l_part[4] = {0.f, 0.f, 0.f, 0.f};

    const __hip_bfloat16* kbase = k_t + ((size_t)b * N_ + (size_t)js * CHUNK_) * CR_;
    const __hip_bfloat16* hbase = h_n + (size_t)b * CR_ * N_ + (size_t)js * CHUNK_;
    const f32x4 z = {0.f, 0.f, 0.f, 0.f};

    auto loadf = [&](bf16x8* K, bf16x8* H, int jt) {
        const __hip_bfloat16* kp = kbase + (size_t)jt * 64 * CR_ + 8 * h4;
        #pragma unroll
        for (int t = 0; t < 4; ++t)
            K[t] = *(const bf16x8*)(kp + (size_t)(4 * m + t) * CR_);
        const __hip_bfloat16* hp = hbase + jt * 64 + 8 * h4;
        H[0] = *(const bf16x8*)(hp + (size_t)m * N_);
        H[1] = *(const bf16x8*)(hp + (size_t)(16 + m) * N_);
        H[2] = *(const bf16x8*)(hp + 32 + (size_t)m * N_);
        H[3] = *(const bf16x8*)(hp + 32 + (size_t)(16 + m) * N_);
    };

    auto compute = [&](const bf16x8* K, const bf16x8* H) {
        f32x4 s[4];
        #pragma unroll
        for (int t = 0; t < 4; ++t)
            s[t] = __builtin_amdgcn_mfma_f32_16x16x32_bf16(qa, K[t], z, 0, 0, 0);

        float mt[4];
        #pragma unroll
        for (int r = 0; r < 4; ++r)
            mt[r] = fmaxf(fmaxf(s[0][r], s[1][r]), fmaxf(s[2][r], s[3][r]));
        const float dmax = fmaxf(fmaxf(mt[0] - m_run[0], mt[1] - m_run[1]),
                                 fmaxf(mt[2] - m_run[2], mt[3] - m_run[3]));
        if (__any(dmax > 8.0f)) {
            #pragma unroll
            for (int r = 0; r < 4; ++r) {
                float v = mt[r];
                v = fmaxf(v, __shfl_xor(v, 1));
                v = fmaxf(v, __shfl_xor(v, 2));
                v = fmaxf(v, __shfl_xor(v, 4));
                v = fmaxf(v, __shfl_xor(v, 8));
                const float mn = fmaxf(m_run[r], v);
                const float sc = fast_exp2(m_run[r] - mn);
                m_run[r] = mn;
                l_part[r] *= sc;
                acc0[r] *= sc;
                acc1[r] *= sc;
            }
        }

        #pragma unroll
        for (int r = 0; r < 4; ++r) {
            const float p0 = fast_exp2(s[0][r] - m_run[r]);
            const float p1 = fast_exp2(s[1][r] - m_run[r]);
            const float p2 = fast_exp2(s[2][r] - m_run[r]);
            const float p3 = fast_exp2(s[3][r] - m_run[r]);
            l_part[r] += (p0 + p1) + (p2 + p3);
            uint2 v;
            v.x = cvt_pk_bf16(p0, p1);
            v.y = cvt_pk_bf16(p2, p3);
            *(uint2*)&p_lds[w][4 * h4 + r][4 * m] = v;  // cols 4m..4m+3 = j_local
        }

        const bf16x8 pa0 = *(const bf16x8*)&p_lds[w][m][8 * h4];
        const bf16x8 pa1 = *(const bf16x8*)&p_lds[w][m][32 + 8 * h4];

        acc0 = __builtin_amdgcn_mfma_f32_16x16x32_bf16(pa0, H[0], acc0, 0, 0, 0);
        acc0 = __builtin_amdgcn_mfma_f32_16x16x32_bf16(pa1, H[2], acc0, 0, 0, 0);
        acc1 = __builtin_amdgcn_mfma_f32_16x16x32_bf16(pa0, H[1], acc1, 0, 0, 0);
        acc1 = __builtin_amdgcn_mfma_f32_16x16x32_bf16(pa1, H[3], acc1, 0, 0, 0);
    };

    bf16x8 kA[4], hA[4], kB[4], hB[4];
    loadf(kA, hA, 0);
    #pragma unroll 1
    for (int jt = 0; jt < NT_; jt += 2) {
        loadf(kB, hB, jt + 1);        // prefetch overlaps compute(A)
        compute(kA, hA);
        if (jt + 2 < NT_) loadf(kA, hA, jt + 2);
        compute(kB, hB);
    }

    // ---- epilogue: reduce l across the 16-lane row groups, dump partials ----
    float l_row[4];
    #pragma unroll
    for (int r = 0; r < 4; ++r) {
        float v = l_part[r];
        v += __shfl_xor(v, 1);
        v += __shfl_xor(v, 2);
        v += __shfl_xor(v, 4);
        v += __shfl_xor(v, 8);
        l_row[r] = v;
    }
    float* wa = ws_acc + (((size_t)b * JS_ + js) * CR_ + m) * N_ + iw + 4 * h4;
    *(f32x4*)wa = acc0;                    // cr = m,    i = iw+4*h4+r
    *(f32x4*)(wa + (size_t)16 * N_) = acc1;  // cr = 16+m
    if (m == 0) {
        const size_t base = ((size_t)b * JS_ + js) * 2 * N_ + iw + 4 * h4;
        #pragma unroll
        for (int r = 0; r < 4; ++r) {
            ws_ml[base + r]      = m_run[r];
            ws_ml[base + N_ + r] = l_row[r];
        }
    }
}

// ---------------------------------------------------------------------------
// Combine kernel: merge JS partial flash states (exact), then fused output
// projection y = gamma*(Wo @ out + bo) + x. grid (N/64, B), block 512.
// ---------------------------------------------------------------------------
__global__ __launch_bounds__(512) void combine_kernel(
    const float* __restrict__ ws_acc, const float* __restrict__ ws_ml,
    const float* __restrict__ x,
    const float* __restrict__ Wo, const float* __restrict__ bo,
    const float* __restrict__ gamma_p,
    float* __restrict__ y)
{
    __shared__ float vals_lds[32][64];

    const int tid = threadIdx.x;
    const int il  = tid & 63;
    const int grp = __builtin_amdgcn_readfirstlane(tid >> 6);  // 0..7
    const int b   = blockIdx.y;
    const int i0  = blockIdx.x * 64;
    const int i   = i0 + il;

    // ---- softmax-state combine (each wave handles 4 cr rows) ----
    float mC[JS_], lC[JS_];
    #pragma unroll
    for (int c = 0; c < JS_; ++c) {
        const size_t base = ((size_t)b * JS_ + c) * 2 * N_;
        mC[c] = ws_ml[base + i];
        lC[c] = ws_ml[base + N_ + i];
    }
    const float mf = fmaxf(fmaxf(mC[0], mC[1]), fmaxf(mC[2], mC[3]));
    float wgt[JS_];
    float denom = 0.f;
    #pragma unroll
    for (int c = 0; c < JS_; ++c) {
        wgt[c] = fast_exp2(mC[c] - mf);
        denom += lC[c] * wgt[c];
    }
    const float inv = 1.0f / denom;

    #pragma unroll
    for (int k = 0; k < 4; ++k) {
        const int cr = 4 * grp + k;
        float a = 0.f;
        #pragma unroll
        for (int c = 0; c < JS_; ++c)
            a += ws_acc[(((size_t)b * JS_ + c) * CR_ + cr) * N_ + i] * wgt[c];
        vals_lds[cr][il] = a * inv;
    }
    __syncthreads();

    float vals[32];
    #pragma unroll
    for (int cr = 0; cr < 32; ++cr) vals[cr] = vals_lds[cr][il];

    // ---- output projection + residual (each wave handles 32 out channels) ----
    const float gmv = gamma_p[0];
    const float* xb = x + (size_t)b * C_ * N_ + i;
    float* yb = y + (size_t)b * C_ * N_ + i;
    for (int k = 0; k < 32; ++k) {
        const int co = grp * 32 + k;
        const float* wr = Wo + (size_t)co * CR_;
        float a = bo[co];
        #pragma unroll
        for (int q = 0; q < 8; ++q) {
            const float4 w4 = *(const float4*)&wr[4 * q];
            a += w4.x * vals[4 * q] + w4.y * vals[4 * q + 1] +
                 w4.z * vals[4 * q + 2] + w4.w * vals[4 * q + 3];
        }
        yb[(size_t)co * N_] = gmv * a + xb[(size_t)co * N_];
    }
}

extern "C" void kernel_launch(void* const* d_in, const int* in_sizes, int n_in,
                              void* d_out, int out_size, void* d_ws, size_t ws_size,
                              hipStream_t stream) {
    (void)in_sizes; (void)n_in; (void)out_size; (void)ws_size;
    const float* x  = (const float*)d_in[0];
    const float* Wv = (const float*)d_in[1];
    const float* bv = (const float*)d_in[2];
    const float* Wk = (const float*)d_in[3];
    const float* bk = (const float*)d_in[4];
    const float* Wq = (const float*)d_in[5];
    const float* bq = (const float*)d_in[6];
    const float* Wo = (const float*)d_in[7];
    const float* bo = (const float*)d_in[8];
    const float* gm = (const float*)d_in[9];
    float* y = (float*)d_out;

    __hip_bfloat16* q_t = (__hip_bfloat16*)d_ws;          // f*log2e, [B][N][CR]
    __hip_bfloat16* k_t = q_t + (size_t)B_ * N_ * CR_;    // g,       [B][N][CR]
    __hip_bfloat16* h_n = k_t + (size_t)B_ * N_ * CR_;    // h,       [B][CR][N]
    float* ws_acc = (float*)(h_n + (size_t)B_ * CR_ * N_);            // [B][JS][CR][N]
    float* ws_ml  = ws_acc + (size_t)B_ * JS_ * CR_ * N_;             // [B][JS][2][N]

    proj_kernel<<<dim3(N_ / 64, B_), 512, 0, stream>>>(x, Wv, bv, Wk, bk, Wq, bq,
                                                       q_t, k_t, h_n);
    flash_kernel<<<dim3(N_ / 64, B_, JS_), 256, 0, stream>>>(q_t, k_t, h_n,
                                                             ws_acc, ws_ml);
    combine_kernel<<<dim3(N_ / 64, B_), 512, 0, stream>>>(ws_acc, ws_ml, x,
                                                          Wo, bo, gm, y);
}

// Round 4
// 172.466 us; speedup vs baseline: 1.4185x; 1.1430x over previous
//
#include <hip/hip_runtime.h>
#include <hip/hip_bf16.h>
#include <stdint.h>

#define B_ 4
#define C_ 256
#define N_ 4096
#define CR_ 32
#define JS_ 4                 // j-split factor
#define CHUNK_ (N_ / JS_)     // 1024 j's per chunk
#define NT_ (CHUNK_ / 64)     // 16 tiles per chunk
#define LOG2E_F 1.44269504088896340736f

typedef __attribute__((ext_vector_type(8))) short bf16x8;
typedef __attribute__((ext_vector_type(4))) float f32x4;

__device__ __forceinline__ uint32_t cvt_pk_bf16(float lo, float hi) {
    uint32_t r;
    asm("v_cvt_pk_bf16_f32 %0, %1, %2" : "=v"(r) : "v"(lo), "v"(hi));
    return r;
}

__device__ __forceinline__ float fast_exp2(float x) {
#if __has_builtin(__builtin_amdgcn_exp2f)
    return __builtin_amdgcn_exp2f(x);
#else
    return exp2f(x);
#endif
}

// ---------------------------------------------------------------------------
// W convert: Wb[96][256] = {Wv*log2e, Wk, Wq} bf16. grid 96 x 256.
// ---------------------------------------------------------------------------
__global__ __launch_bounds__(256) void convw_kernel(
    const float* __restrict__ Wv, const float* __restrict__ Wk,
    const float* __restrict__ Wq, __hip_bfloat16* __restrict__ Wb)
{
    const int idx = blockIdx.x * 256 + threadIdx.x;  // < 24576
    if (idx < 8192)        Wb[idx] = __float2bfloat16(Wv[idx] * LOG2E_F);
    else if (idx < 16384)  Wb[idx] = __float2bfloat16(Wk[idx - 8192]);
    else                   Wb[idx] = __float2bfloat16(Wq[idx - 16384]);
}

// ---------------------------------------------------------------------------
// Projection via MFMA. grid (N/64, B), block 512 (8 waves).
// Wave w: n-slice ns=w&3 (16 n), channel-group mg=w>>2 (16 ch of f,g,h each).
// B-frags: x cast to bf16 in-reg from global. A-frags: Wb rows from L2.
//   f -> q_t[b][n][cr] (pre-scaled by log2e), g -> k_t[b][n][cr],
//   h -> h_n[b][cr][n].  f,g transposed via LDS for coalesced b128 stores.
// ---------------------------------------------------------------------------
__global__ __launch_bounds__(512) void proj_kernel(
    const __hip_bfloat16* __restrict__ Wb,
    const float* __restrict__ bv, const float* __restrict__ bk,
    const float* __restrict__ bq,
    const float* __restrict__ x,
    __hip_bfloat16* __restrict__ q_t, __hip_bfloat16* __restrict__ k_t,
    __hip_bfloat16* __restrict__ h_n)
{
    __shared__ uint32_t tq[4][16][44];  // [ns][n-local][cr-dword], 176B rows
    __shared__ uint32_t tk[4][16][44];

    const int tid  = threadIdx.x;
    const int lane = tid & 63;
    const int w    = __builtin_amdgcn_readfirstlane(tid >> 6);
    const int ns   = w & 3;
    const int mg   = w >> 2;
    const int b    = blockIdx.y;
    const int n0   = blockIdx.x * 64;
    const int m    = lane & 15;
    const int h4   = lane >> 4;
    const int ncol = n0 + 16 * ns + m;

    // ---- B fragments: x[32s+8h4+e][ncol] -> bf16, 8 K-steps ----
    bf16x8 bfr[8];
    #pragma unroll
    for (int s = 0; s < 8; ++s) {
        const float* xp = x + ((size_t)b * C_ + 32 * s + 8 * h4) * N_ + ncol;
        float xe[8];
        #pragma unroll
        for (int e = 0; e < 8; ++e) xe[e] = xp[(size_t)e * N_];
        uint4 u;
        u.x = cvt_pk_bf16(xe[0], xe[1]);
        u.y = cvt_pk_bf16(xe[2], xe[3]);
        u.z = cvt_pk_bf16(xe[4], xe[5]);
        u.w = cvt_pk_bf16(xe[6], xe[7]);
        bfr[s] = __builtin_bit_cast(bf16x8, u);
    }

    // ---- 3 interleaved MFMA chains (f, g, h), bias as C-init ----
    const int mrow = 16 * mg;
    const float4 b4v = *(const float4*)&bv[mrow + 4 * h4];
    const float4 b4k = *(const float4*)&bk[mrow + 4 * h4];
    const float4 b4q = *(const float4*)&bq[mrow + 4 * h4];
    f32x4 accF = {b4v.x * LOG2E_F, b4v.y * LOG2E_F, b4v.z * LOG2E_F, b4v.w * LOG2E_F};
    f32x4 accG = {b4k.x, b4k.y, b4k.z, b4k.w};
    f32x4 accH = {b4q.x, b4q.y, b4q.z, b4q.w};
    const __hip_bfloat16* wF = Wb + (size_t)(mrow + m) * 256;
    const __hip_bfloat16* wG = wF + (size_t)32 * 256;
    const __hip_bfloat16* wH = wG + (size_t)32 * 256;
    #pragma unroll
    for (int s = 0; s < 8; ++s) {
        const bf16x8 aF = *(const bf16x8*)(wF + 32 * s + 8 * h4);
        const bf16x8 aG = *(const bf16x8*)(wG + 32 * s + 8 * h4);
        const bf16x8 aH = *(const bf16x8*)(wH + 32 * s + 8 * h4);
        accF = __builtin_amdgcn_mfma_f32_16x16x32_bf16(aF, bfr[s], accF, 0, 0, 0);
        accG = __builtin_amdgcn_mfma_f32_16x16x32_bf16(aG, bfr[s], accG, 0, 0, 0);
        accH = __builtin_amdgcn_mfma_f32_16x16x32_bf16(aH, bfr[s], accH, 0, 0, 0);
    }

    // ---- f,g -> LDS transpose; h -> direct store ----
    // D element r <-> channel = mrow + 4*h4 + r, col n-local = m.
    tq[ns][m][8 * mg + 2 * h4 + 0] = cvt_pk_bf16(accF[0], accF[1]);
    tq[ns][m][8 * mg + 2 * h4 + 1] = cvt_pk_bf16(accF[2], accF[3]);
    tk[ns][m][8 * mg + 2 * h4 + 0] = cvt_pk_bf16(accG[0], accG[1]);
    tk[ns][m][8 * mg + 2 * h4 + 1] = cvt_pk_bf16(accG[2], accG[3]);
    #pragma unroll
    for (int r = 0; r < 4; ++r) {
        const int ch = mrow + 4 * h4 + r;
        h_n[((size_t)b * CR_ + ch) * N_ + ncol] = __float2bfloat16(accH[r]);
    }
    __syncthreads();

    // ---- cooperative coalesced q/k stores: waves 0-3 -> q, 4-7 -> k ----
    {
        const int sl = w & 3;
        const uint32_t* src = (w < 4) ? &tq[sl][0][0] : &tk[sl][0][0];
        const uint4 val = *(const uint4*)(src + m * 44 + 4 * h4);
        __hip_bfloat16* dst = ((w < 4) ? q_t : k_t) +
            ((size_t)b * N_ + n0 + 16 * sl + m) * CR_ + 8 * h4;
        *(uint4*)dst = val;
    }
}

// ---------------------------------------------------------------------------
// Flash attention, j-split. grid (N/64, B, JS), block 256 (4 waves).
// BYTE-IDENTICAL logic to round 2 (proven).
// ---------------------------------------------------------------------------
__global__ __launch_bounds__(256, 4) void flash_kernel(
    const __hip_bfloat16* __restrict__ q_t,
    const __hip_bfloat16* __restrict__ k_t,
    const __hip_bfloat16* __restrict__ h_n,
    float* __restrict__ ws_acc,   // [B][JS][CR][N]
    float* __restrict__ ws_ml)    // [B][JS][2][N]
{
    __shared__ __hip_bfloat16 p_lds[4][16][72];

    const int tid  = threadIdx.x;
    const int lane = tid & 63;
    const int w    = __builtin_amdgcn_readfirstlane(tid >> 6);
    const int b    = blockIdx.y;
    const int js   = blockIdx.z;
    const int i0   = blockIdx.x * 64;
    const int iw   = i0 + w * 16;

    const int m  = lane & 15;
    const int h4 = lane >> 4;

    const bf16x8 qa = *(const bf16x8*)(q_t + ((size_t)b * N_ + iw + m) * CR_ + 8 * h4);

    f32x4 acc0 = {0.f, 0.f, 0.f, 0.f};
    f32x4 acc1 = {0.f, 0.f, 0.f, 0.f};
    float m_run[4]  = {-INFINITY, -INFINITY, -INFINITY, -INFINITY};
    float l_part[4] = {0.f, 0.f, 0.f, 0.f};

    const __hip_bfloat16* kbase = k_t + ((size_t)b * N_ + (size_t)js * CHUNK_) * CR_;
    const __hip_bfloat16* hbase = h_n + (size_t)b * CR_ * N_ + (size_t)js * CHUNK_;
    const f32x4 z = {0.f, 0.f, 0.f, 0.f};

    auto loadf = [&](bf16x8* K, bf16x8* H, int jt) {
        const __hip_bfloat16* kp = kbase + (size_t)jt * 64 * CR_ + 8 * h4;
        #pragma unroll
        for (int t = 0; t < 4; ++t)
            K[t] = *(const bf16x8*)(kp + (size_t)(4 * m + t) * CR_);
        const __hip_bfloat16* hp = hbase + jt * 64 + 8 * h4;
        H[0] = *(const bf16x8*)(hp + (size_t)m * N_);
        H[1] = *(const bf16x8*)(hp + (size_t)(16 + m) * N_);
        H[2] = *(const bf16x8*)(hp + 32 + (size_t)m * N_);
        H[3] = *(const bf16x8*)(hp + 32 + (size_t)(16 + m) * N_);
    };

    auto compute = [&](const bf16x8* K, const bf16x8* H) {
        f32x4 s[4];
        #pragma unroll
        for (int t = 0; t < 4; ++t)
            s[t] = __builtin_amdgcn_mfma_f32_16x16x32_bf16(qa, K[t], z, 0, 0, 0);

        float mt[4];
        #pragma unroll
        for (int r = 0; r < 4; ++r)
            mt[r] = fmaxf(fmaxf(s[0][r], s[1][r]), fmaxf(s[2][r], s[3][r]));
        const float dmax = fmaxf(fmaxf(mt[0] - m_run[0], mt[1] - m_run[1]),
                                 fmaxf(mt[2] - m_run[2], mt[3] - m_run[3]));
        if (__any(dmax > 8.0f)) {
            #pragma unroll
            for (int r = 0; r < 4; ++r) {
                float v = mt[r];
                v = fmaxf(v, __shfl_xor(v, 1));
                v = fmaxf(v, __shfl_xor(v, 2));
                v = fmaxf(v, __shfl_xor(v, 4));
                v = fmaxf(v, __shfl_xor(v, 8));
                const float mn = fmaxf(m_run[r], v);
                const float sc = fast_exp2(m_run[r] - mn);
                m_run[r] = mn;
                l_part[r] *= sc;
                acc0[r] *= sc;
                acc1[r] *= sc;
            }
        }

        #pragma unroll
        for (int r = 0; r < 4; ++r) {
            const float p0 = fast_exp2(s[0][r] - m_run[r]);
            const float p1 = fast_exp2(s[1][r] - m_run[r]);
            const float p2 = fast_exp2(s[2][r] - m_run[r]);
            const float p3 = fast_exp2(s[3][r] - m_run[r]);
            l_part[r] += (p0 + p1) + (p2 + p3);
            uint2 v;
            v.x = cvt_pk_bf16(p0, p1);
            v.y = cvt_pk_bf16(p2, p3);
            *(uint2*)&p_lds[w][4 * h4 + r][4 * m] = v;
        }

        const bf16x8 pa0 = *(const bf16x8*)&p_lds[w][m][8 * h4];
        const bf16x8 pa1 = *(const bf16x8*)&p_lds[w][m][32 + 8 * h4];

        acc0 = __builtin_amdgcn_mfma_f32_16x16x32_bf16(pa0, H[0], acc0, 0, 0, 0);
        acc0 = __builtin_amdgcn_mfma_f32_16x16x32_bf16(pa1, H[2], acc0, 0, 0, 0);
        acc1 = __builtin_amdgcn_mfma_f32_16x16x32_bf16(pa0, H[1], acc1, 0, 0, 0);
        acc1 = __builtin_amdgcn_mfma_f32_16x16x32_bf16(pa1, H[3], acc1, 0, 0, 0);
    };

    bf16x8 kA[4], hA[4], kB[4], hB[4];
    loadf(kA, hA, 0);
    #pragma unroll 1
    for (int jt = 0; jt < NT_; jt += 2) {
        loadf(kB, hB, jt + 1);
        compute(kA, hA);
        if (jt + 2 < NT_) loadf(kA, hA, jt + 2);
        compute(kB, hB);
    }

    float l_row[4];
    #pragma unroll
    for (int r = 0; r < 4; ++r) {
        float v = l_part[r];
        v += __shfl_xor(v, 1);
        v += __shfl_xor(v, 2);
        v += __shfl_xor(v, 4);
        v += __shfl_xor(v, 8);
        l_row[r] = v;
    }
    float* wa = ws_acc + (((size_t)b * JS_ + js) * CR_ + m) * N_ + iw + 4 * h4;
    *(f32x4*)wa = acc0;
    *(f32x4*)(wa + (size_t)16 * N_) = acc1;
    if (m == 0) {
        const size_t base = ((size_t)b * JS_ + js) * 2 * N_ + iw + 4 * h4;
        #pragma unroll
        for (int r = 0; r < 4; ++r) {
            ws_ml[base + r]      = m_run[r];
            ws_ml[base + N_ + r] = l_row[r];
        }
    }
}

// ---------------------------------------------------------------------------
// Combine: BYTE-IDENTICAL logic to round 2 (proven). grid (N/64, B), block 512.
// ---------------------------------------------------------------------------
__global__ __launch_bounds__(512) void combine_kernel(
    const float* __restrict__ ws_acc, const float* __restrict__ ws_ml,
    const float* __restrict__ x,
    const float* __restrict__ Wo, const float* __restrict__ bo,
    const float* __restrict__ gamma_p,
    float* __restrict__ y)
{
    __shared__ float vals_lds[32][64];

    const int tid = threadIdx.x;
    const int il  = tid & 63;
    const int grp = __builtin_amdgcn_readfirstlane(tid >> 6);  // 0..7
    const int b   = blockIdx.y;
    const int i0  = blockIdx.x * 64;
    const int i   = i0 + il;

    float mC[JS_], lC[JS_];
    #pragma unroll
    for (int c = 0; c < JS_; ++c) {
        const size_t base = ((size_t)b * JS_ + c) * 2 * N_;
        mC[c] = ws_ml[base + i];
        lC[c] = ws_ml[base + N_ + i];
    }
    const float mf = fmaxf(fmaxf(mC[0], mC[1]), fmaxf(mC[2], mC[3]));
    float wgt[JS_];
    float denom = 0.f;
    #pragma unroll
    for (int c = 0; c < JS_; ++c) {
        wgt[c] = fast_exp2(mC[c] - mf);
        denom += lC[c] * wgt[c];
    }
    const float inv = 1.0f / denom;

    #pragma unroll
    for (int k = 0; k < 4; ++k) {
        const int cr = 4 * grp + k;
        float a = 0.f;
        #pragma unroll
        for (int c = 0; c < JS_; ++c)
            a += ws_acc[(((size_t)b * JS_ + c) * CR_ + cr) * N_ + i] * wgt[c];
        vals_lds[cr][il] = a * inv;
    }
    __syncthreads();

    float vals[32];
    #pragma unroll
    for (int cr = 0; cr < 32; ++cr) vals[cr] = vals_lds[cr][il];

    const float gmv = gamma_p[0];
    const float* xb = x + (size_t)b * C_ * N_ + i;
    float* yb = y + (size_t)b * C_ * N_ + i;
    for (int k = 0; k < 32; ++k) {
        const int co = grp * 32 + k;
        const float* wr = Wo + (size_t)co * CR_;
        float a = bo[co];
        #pragma unroll
        for (int q = 0; q < 8; ++q) {
            const float4 w4 = *(const float4*)&wr[4 * q];
            a += w4.x * vals[4 * q] + w4.y * vals[4 * q + 1] +
                 w4.z * vals[4 * q + 2] + w4.w * vals[4 * q + 3];
        }
        yb[(size_t)co * N_] = gmv * a + xb[(size_t)co * N_];
    }
}

extern "C" void kernel_launch(void* const* d_in, const int* in_sizes, int n_in,
                              void* d_out, int out_size, void* d_ws, size_t ws_size,
                              hipStream_t stream) {
    (void)in_sizes; (void)n_in; (void)out_size; (void)ws_size;
    const float* x  = (const float*)d_in[0];
    const float* Wv = (const float*)d_in[1];
    const float* bv = (const float*)d_in[2];
    const float* Wk = (const float*)d_in[3];
    const float* bk = (const float*)d_in[4];
    const float* Wq = (const float*)d_in[5];
    const float* bq = (const float*)d_in[6];
    const float* Wo = (const float*)d_in[7];
    const float* bo = (const float*)d_in[8];
    const float* gm = (const float*)d_in[9];
    float* y = (float*)d_out;

    __hip_bfloat16* q_t = (__hip_bfloat16*)d_ws;          // f*log2e, [B][N][CR]
    __hip_bfloat16* k_t = q_t + (size_t)B_ * N_ * CR_;    // g,       [B][N][CR]
    __hip_bfloat16* h_n = k_t + (size_t)B_ * N_ * CR_;    // h,       [B][CR][N]
    __hip_bfloat16* Wb  = h_n + (size_t)B_ * CR_ * N_;    // [96][256] bf16
    float* ws_acc = (float*)(Wb + (size_t)96 * 256);      // [B][JS][CR][N]
    float* ws_ml  = ws_acc + (size_t)B_ * JS_ * CR_ * N_; // [B][JS][2][N]

    convw_kernel<<<96, 256, 0, stream>>>(Wv, Wk, Wq, Wb);
    proj_kernel<<<dim3(N_ / 64, B_), 512, 0, stream>>>(Wb, bv, bk, bq, x,
                                                       q_t, k_t, h_n);
    flash_kernel<<<dim3(N_ / 64, B_, JS_), 256, 0, stream>>>(q_t, k_t, h_n,
                                                             ws_acc, ws_ml);
    combine_kernel<<<dim3(N_ / 64, B_), 512, 0, stream>>>(ws_acc, ws_ml, x,
                                                          Wo, bo, gm, y);
}

// Round 5
// 168.357 us; speedup vs baseline: 1.4531x; 1.0244x over previous
//
#include <hip/hip_runtime.h>
#include <hip/hip_bf16.h>
#include <stdint.h>

#define B_ 4
#define C_ 256
#define N_ 4096
#define CR_ 32
#define LOG2E_F 1.44269504088896340736f

typedef __attribute__((ext_vector_type(8))) short bf16x8;
typedef __attribute__((ext_vector_type(4))) float f32x4;

__device__ __forceinline__ uint32_t cvt_pk_bf16(float lo, float hi) {
    uint32_t r;
    asm("v_cvt_pk_bf16_f32 %0, %1, %2" : "=v"(r) : "v"(lo), "v"(hi));
    return r;
}

__device__ __forceinline__ float fast_exp2(float x) {
#if __has_builtin(__builtin_amdgcn_exp2f)
    return __builtin_amdgcn_exp2f(x);
#else
    return exp2f(x);
#endif
}

// ---------------------------------------------------------------------------
// W convert: Wb[96][256] = {Wv*log2e, Wk, Wq} bf16. grid 96 x 256.
// (byte-identical to round 4 — proven)
// ---------------------------------------------------------------------------
__global__ __launch_bounds__(256) void convw_kernel(
    const float* __restrict__ Wv, const float* __restrict__ Wk,
    const float* __restrict__ Wq, __hip_bfloat16* __restrict__ Wb)
{
    const int idx = blockIdx.x * 256 + threadIdx.x;  // < 24576
    if (idx < 8192)        Wb[idx] = __float2bfloat16(Wv[idx] * LOG2E_F);
    else if (idx < 16384)  Wb[idx] = __float2bfloat16(Wk[idx - 8192]);
    else                   Wb[idx] = __float2bfloat16(Wq[idx - 16384]);
}

// ---------------------------------------------------------------------------
// Projection via MFMA. grid (N/64, B), block 512 (8 waves).
// (byte-identical to round 4 — proven)
// ---------------------------------------------------------------------------
__global__ __launch_bounds__(512) void proj_kernel(
    const __hip_bfloat16* __restrict__ Wb,
    const float* __restrict__ bv, const float* __restrict__ bk,
    const float* __restrict__ bq,
    const float* __restrict__ x,
    __hip_bfloat16* __restrict__ q_t, __hip_bfloat16* __restrict__ k_t,
    __hip_bfloat16* __restrict__ h_n)
{
    __shared__ uint32_t tq[4][16][44];  // [ns][n-local][cr-dword], 176B rows
    __shared__ uint32_t tk[4][16][44];

    const int tid  = threadIdx.x;
    const int lane = tid & 63;
    const int w    = __builtin_amdgcn_readfirstlane(tid >> 6);
    const int ns   = w & 3;
    const int mg   = w >> 2;
    const int b    = blockIdx.y;
    const int n0   = blockIdx.x * 64;
    const int m    = lane & 15;
    const int h4   = lane >> 4;
    const int ncol = n0 + 16 * ns + m;

    // ---- B fragments: x[32s+8h4+e][ncol] -> bf16, 8 K-steps ----
    bf16x8 bfr[8];
    #pragma unroll
    for (int s = 0; s < 8; ++s) {
        const float* xp = x + ((size_t)b * C_ + 32 * s + 8 * h4) * N_ + ncol;
        float xe[8];
        #pragma unroll
        for (int e = 0; e < 8; ++e) xe[e] = xp[(size_t)e * N_];
        uint4 u;
        u.x = cvt_pk_bf16(xe[0], xe[1]);
        u.y = cvt_pk_bf16(xe[2], xe[3]);
        u.z = cvt_pk_bf16(xe[4], xe[5]);
        u.w = cvt_pk_bf16(xe[6], xe[7]);
        bfr[s] = __builtin_bit_cast(bf16x8, u);
    }

    // ---- 3 interleaved MFMA chains (f, g, h), bias as C-init ----
    const int mrow = 16 * mg;
    const float4 b4v = *(const float4*)&bv[mrow + 4 * h4];
    const float4 b4k = *(const float4*)&bk[mrow + 4 * h4];
    const float4 b4q = *(const float4*)&bq[mrow + 4 * h4];
    f32x4 accF = {b4v.x * LOG2E_F, b4v.y * LOG2E_F, b4v.z * LOG2E_F, b4v.w * LOG2E_F};
    f32x4 accG = {b4k.x, b4k.y, b4k.z, b4k.w};
    f32x4 accH = {b4q.x, b4q.y, b4q.z, b4q.w};
    const __hip_bfloat16* wF = Wb + (size_t)(mrow + m) * 256;
    const __hip_bfloat16* wG = wF + (size_t)32 * 256;
    const __hip_bfloat16* wH = wG + (size_t)32 * 256;
    #pragma unroll
    for (int s = 0; s < 8; ++s) {
        const bf16x8 aF = *(const bf16x8*)(wF + 32 * s + 8 * h4);
        const bf16x8 aG = *(const bf16x8*)(wG + 32 * s + 8 * h4);
        const bf16x8 aH = *(const bf16x8*)(wH + 32 * s + 8 * h4);
        accF = __builtin_amdgcn_mfma_f32_16x16x32_bf16(aF, bfr[s], accF, 0, 0, 0);
        accG = __builtin_amdgcn_mfma_f32_16x16x32_bf16(aG, bfr[s], accG, 0, 0, 0);
        accH = __builtin_amdgcn_mfma_f32_16x16x32_bf16(aH, bfr[s], accH, 0, 0, 0);
    }

    // ---- f,g -> LDS transpose; h -> direct store ----
    tq[ns][m][8 * mg + 2 * h4 + 0] = cvt_pk_bf16(accF[0], accF[1]);
    tq[ns][m][8 * mg + 2 * h4 + 1] = cvt_pk_bf16(accF[2], accF[3]);
    tk[ns][m][8 * mg + 2 * h4 + 0] = cvt_pk_bf16(accG[0], accG[1]);
    tk[ns][m][8 * mg + 2 * h4 + 1] = cvt_pk_bf16(accG[2], accG[3]);
    #pragma unroll
    for (int r = 0; r < 4; ++r) {
        const int ch = mrow + 4 * h4 + r;
        h_n[((size_t)b * CR_ + ch) * N_ + ncol] = __float2bfloat16(accH[r]);
    }
    __syncthreads();

    // ---- cooperative coalesced q/k stores: waves 0-3 -> q, 4-7 -> k ----
    {
        const int sl = w & 3;
        const uint32_t* src = (w < 4) ? &tq[sl][0][0] : &tk[sl][0][0];
        const uint4 val = *(const uint4*)(src + m * 44 + 4 * h4);
        __hip_bfloat16* dst = ((w < 4) ? q_t : k_t) +
            ((size_t)b * N_ + n0 + 16 * sl + m) * CR_ + 8 * h4;
        *(uint4*)dst = val;
    }
}

// ---------------------------------------------------------------------------
// Flash attention, j-split. grid (N/64, B, JS), block 256 (4 waves).
// Body identical to the proven round-2/4 kernel; JS is a template param.
// launch_bounds stays (256,4) — regalloc promise only; 64 VGPR + 9KB LDS
// allow 8 blocks/CU at runtime.
// ---------------------------------------------------------------------------
template <int JS>
__global__ __launch_bounds__(256, 4) void flash_kernel(
    const __hip_bfloat16* __restrict__ q_t,
    const __hip_bfloat16* __restrict__ k_t,
    const __hip_bfloat16* __restrict__ h_n,
    float* __restrict__ ws_acc,   // [B][JS][CR][N]
    float* __restrict__ ws_ml)    // [B][JS][2][N]
{
    constexpr int CHUNK = N_ / JS;
    constexpr int NT    = CHUNK / 64;

    __shared__ __hip_bfloat16 p_lds[4][16][72];

    const int tid  = threadIdx.x;
    const int lane = tid & 63;
    const int w    = __builtin_amdgcn_readfirstlane(tid >> 6);
    const int b    = blockIdx.y;
    const int js   = blockIdx.z;
    const int i0   = blockIdx.x * 64;
    const int iw   = i0 + w * 16;

    const int m  = lane & 15;
    const int h4 = lane >> 4;

    const bf16x8 qa = *(const bf16x8*)(q_t + ((size_t)b * N_ + iw + m) * CR_ + 8 * h4);

    f32x4 acc0 = {0.f, 0.f, 0.f, 0.f};
    f32x4 acc1 = {0.f, 0.f, 0.f, 0.f};
    float m_run[4]  = {-INFINITY, -INFINITY, -INFINITY, -INFINITY};
    float l_part[4] = {0.f, 0.f, 0.f, 0.f};

    const __hip_bfloat16* kbase = k_t + ((size_t)b * N_ + (size_t)js * CHUNK) * CR_;
    const __hip_bfloat16* hbase = h_n + (size_t)b * CR_ * N_ + (size_t)js * CHUNK;
    const f32x4 z = {0.f, 0.f, 0.f, 0.f};

    auto loadf = [&](bf16x8* K, bf16x8* H, int jt) {
        const __hip_bfloat16* kp = kbase + (size_t)jt * 64 * CR_ + 8 * h4;
        #pragma unroll
        for (int t = 0; t < 4; ++t)
            K[t] = *(const bf16x8*)(kp + (size_t)(4 * m + t) * CR_);
        const __hip_bfloat16* hp = hbase + jt * 64 + 8 * h4;
        H[0] = *(const bf16x8*)(hp + (size_t)m * N_);
        H[1] = *(const bf16x8*)(hp + (size_t)(16 + m) * N_);
        H[2] = *(const bf16x8*)(hp + 32 + (size_t)m * N_);
        H[3] = *(const bf16x8*)(hp + 32 + (size_t)(16 + m) * N_);
    };

    auto compute = [&](const bf16x8* K, const bf16x8* H) {
        f32x4 s[4];
        #pragma unroll
        for (int t = 0; t < 4; ++t)
            s[t] = __builtin_amdgcn_mfma_f32_16x16x32_bf16(qa, K[t], z, 0, 0, 0);

        float mt[4];
        #pragma unroll
        for (int r = 0; r < 4; ++r)
            mt[r] = fmaxf(fmaxf(s[0][r], s[1][r]), fmaxf(s[2][r], s[3][r]));
        const float dmax = fmaxf(fmaxf(mt[0] - m_run[0], mt[1] - m_run[1]),
                                 fmaxf(mt[2] - m_run[2], mt[3] - m_run[3]));
        if (__any(dmax > 8.0f)) {
            #pragma unroll
            for (int r = 0; r < 4; ++r) {
                float v = mt[r];
                v = fmaxf(v, __shfl_xor(v, 1));
                v = fmaxf(v, __shfl_xor(v, 2));
                v = fmaxf(v, __shfl_xor(v, 4));
                v = fmaxf(v, __shfl_xor(v, 8));
                const float mn = fmaxf(m_run[r], v);
                const float sc = fast_exp2(m_run[r] - mn);
                m_run[r] = mn;
                l_part[r] *= sc;
                acc0[r] *= sc;
                acc1[r] *= sc;
            }
        }

        #pragma unroll
        for (int r = 0; r < 4; ++r) {
            const float p0 = fast_exp2(s[0][r] - m_run[r]);
            const float p1 = fast_exp2(s[1][r] - m_run[r]);
            const float p2 = fast_exp2(s[2][r] - m_run[r]);
            const float p3 = fast_exp2(s[3][r] - m_run[r]);
            l_part[r] += (p0 + p1) + (p2 + p3);
            uint2 v;
            v.x = cvt_pk_bf16(p0, p1);
            v.y = cvt_pk_bf16(p2, p3);
            *(uint2*)&p_lds[w][4 * h4 + r][4 * m] = v;
        }

        const bf16x8 pa0 = *(const bf16x8*)&p_lds[w][m][8 * h4];
        const bf16x8 pa1 = *(const bf16x8*)&p_lds[w][m][32 + 8 * h4];

        acc0 = __builtin_amdgcn_mfma_f32_16x16x32_bf16(pa0, H[0], acc0, 0, 0, 0);
        acc0 = __builtin_amdgcn_mfma_f32_16x16x32_bf16(pa1, H[2], acc0, 0, 0, 0);
        acc1 = __builtin_amdgcn_mfma_f32_16x16x32_bf16(pa0, H[1], acc1, 0, 0, 0);
        acc1 = __builtin_amdgcn_mfma_f32_16x16x32_bf16(pa1, H[3], acc1, 0, 0, 0);
    };

    bf16x8 kA[4], hA[4], kB[4], hB[4];
    loadf(kA, hA, 0);
    #pragma unroll 1
    for (int jt = 0; jt < NT; jt += 2) {
        loadf(kB, hB, jt + 1);
        compute(kA, hA);
        if (jt + 2 < NT) loadf(kA, hA, jt + 2);
        compute(kB, hB);
    }

    float l_row[4];
    #pragma unroll
    for (int r = 0; r < 4; ++r) {
        float v = l_part[r];
        v += __shfl_xor(v, 1);
        v += __shfl_xor(v, 2);
        v += __shfl_xor(v, 4);
        v += __shfl_xor(v, 8);
        l_row[r] = v;
    }
    float* wa = ws_acc + (((size_t)b * JS + js) * CR_ + m) * N_ + iw + 4 * h4;
    *(f32x4*)wa = acc0;
    *(f32x4*)(wa + (size_t)16 * N_) = acc1;
    if (m == 0) {
        const size_t base = ((size_t)b * JS + js) * 2 * N_ + iw + 4 * h4;
        #pragma unroll
        for (int r = 0; r < 4; ++r) {
            ws_ml[base + r]      = m_run[r];
            ws_ml[base + N_ + r] = l_row[r];
        }
    }
}

// ---------------------------------------------------------------------------
// Combine: merge JS partial states (scalar, proven logic), then output
// projection with Wo STAGED IN LDS (uniform broadcast reads, no VMEM wall).
// grid (N/64, B), block 512.
// ---------------------------------------------------------------------------
template <int JS>
__global__ __launch_bounds__(512) void combine_kernel(
    const float* __restrict__ ws_acc, const float* __restrict__ ws_ml,
    const float* __restrict__ x,
    const float* __restrict__ Wo, const float* __restrict__ bo,
    const float* __restrict__ gamma_p,
    float* __restrict__ y)
{
    __shared__ float wo_lds[256][32];   // 32 KB
    __shared__ float vals_lds[32][64];  // 8 KB

    const int tid = threadIdx.x;
    const int il  = tid & 63;
    const int grp = __builtin_amdgcn_readfirstlane(tid >> 6);  // 0..7
    const int b   = blockIdx.y;
    const int i0  = blockIdx.x * 64;
    const int i   = i0 + il;

    // ---- stage Wo[256][32] into LDS (coalesced float4) ----
    #pragma unroll
    for (int k = 0; k < 4; ++k) {
        const int i4 = (tid + 512 * k) * 4;  // 0..32764
        *(float4*)&wo_lds[i4 >> 5][i4 & 31] = *(const float4*)&Wo[i4];
    }

    // ---- phase 1: softmax-state combine (proven scalar logic) ----
    {
        float mC[JS], lC[JS];
        #pragma unroll
        for (int c = 0; c < JS; ++c) {
            const size_t base = ((size_t)b * JS + c) * 2 * N_;
            mC[c] = ws_ml[base + i];
            lC[c] = ws_ml[base + N_ + i];
        }
        float mf = mC[0];
        #pragma unroll
        for (int c = 1; c < JS; ++c) mf = fmaxf(mf, mC[c]);
        float wgt[JS];
        float denom = 0.f;
        #pragma unroll
        for (int c = 0; c < JS; ++c) {
            wgt[c] = fast_exp2(mC[c] - mf);
            denom += lC[c] * wgt[c];
        }
        const float inv = 1.0f / denom;

        #pragma unroll
        for (int k = 0; k < 4; ++k) {
            const int cr = 4 * grp + k;
            float a = 0.f;
            #pragma unroll
            for (int c = 0; c < JS; ++c)
                a += ws_acc[(((size_t)b * JS + c) * CR_ + cr) * N_ + i] * wgt[c];
            vals_lds[cr][il] = a * inv;
        }
    }
    __syncthreads();

    float vals[32];
    #pragma unroll
    for (int cr = 0; cr < 32; ++cr) vals[cr] = vals_lds[cr][il];

    // ---- phase 2: output projection + residual, Wo from LDS ----
    const float gmv = gamma_p[0];
    const float* xb = x + (size_t)b * C_ * N_ + i;
    float* yb = y + (size_t)b * C_ * N_ + i;
    for (int k = 0; k < 32; ++k) {
        const int co = grp * 32 + k;
        const float* wr = &wo_lds[co][0];
        float a = bo[co];
        #pragma unroll
        for (int q = 0; q < 8; ++q) {
            const float4 w4 = *(const float4*)&wr[4 * q];
            a += w4.x * vals[4 * q] + w4.y * vals[4 * q + 1] +
                 w4.z * vals[4 * q + 2] + w4.w * vals[4 * q + 3];
        }
        yb[(size_t)co * N_] = gmv * a + xb[(size_t)co * N_];
    }
}

extern "C" void kernel_launch(void* const* d_in, const int* in_sizes, int n_in,
                              void* d_out, int out_size, void* d_ws, size_t ws_size,
                              hipStream_t stream) {
    (void)in_sizes; (void)n_in; (void)out_size;
    const float* x  = (const float*)d_in[0];
    const float* Wv = (const float*)d_in[1];
    const float* bv = (const float*)d_in[2];
    const float* Wk = (const float*)d_in[3];
    const float* bk = (const float*)d_in[4];
    const float* Wq = (const float*)d_in[5];
    const float* bq = (const float*)d_in[6];
    const float* Wo = (const float*)d_in[7];
    const float* bo = (const float*)d_in[8];
    const float* gm = (const float*)d_in[9];
    float* y = (float*)d_out;

    __hip_bfloat16* q_t = (__hip_bfloat16*)d_ws;          // f*log2e, [B][N][CR]
    __hip_bfloat16* k_t = q_t + (size_t)B_ * N_ * CR_;    // g,       [B][N][CR]
    __hip_bfloat16* h_n = k_t + (size_t)B_ * N_ * CR_;    // h,       [B][CR][N]
    __hip_bfloat16* Wb  = h_n + (size_t)B_ * CR_ * N_;    // [96][256] bf16
    float* ws_acc = (float*)(Wb + (size_t)96 * 256);
    const size_t base_off = (size_t)((char*)ws_acc - (char*)d_ws);
    const size_t need8 = base_off + (size_t)B_ * 8 * CR_ * N_ * 4
                                  + (size_t)B_ * 8 * 2 * N_ * 4;

    convw_kernel<<<96, 256, 0, stream>>>(Wv, Wk, Wq, Wb);
    proj_kernel<<<dim3(N_ / 64, B_), 512, 0, stream>>>(Wb, bv, bk, bq, x,
                                                       q_t, k_t, h_n);

    if (ws_size >= need8) {
        float* ws_ml = ws_acc + (size_t)B_ * 8 * CR_ * N_;
        flash_kernel<8><<<dim3(N_ / 64, B_, 8), 256, 0, stream>>>(q_t, k_t, h_n,
                                                                  ws_acc, ws_ml);
        combine_kernel<8><<<dim3(N_ / 64, B_), 512, 0, stream>>>(ws_acc, ws_ml, x,
                                                                 Wo, bo, gm, y);
    } else {
        float* ws_ml = ws_acc + (size_t)B_ * 4 * CR_ * N_;
        flash_kernel<4><<<dim3(N_ / 64, B_, 4), 256, 0, stream>>>(q_t, k_t, h_n,
                                                                  ws_acc, ws_ml);
        combine_kernel<4><<<dim3(N_ / 64, B_), 512, 0, stream>>>(ws_acc, ws_ml, x,
                                                                 Wo, bo, gm, y);
    }
}

// Round 8
// 139.760 us; speedup vs baseline: 1.7504x; 1.2046x over previous
//
#include <hip/hip_runtime.h>
#include <hip/hip_bf16.h>
#include <stdint.h>

#define B_ 4
#define C_ 256
#define N_ 4096
#define CR_ 32
#define LOG2E_F 1.44269504088896340736f

typedef __attribute__((ext_vector_type(8))) short bf16x8;
typedef __attribute__((ext_vector_type(4))) float f32x4;

__device__ __forceinline__ uint32_t cvt_pk_bf16(float lo, float hi) {
    uint32_t r;
    asm("v_cvt_pk_bf16_f32 %0, %1, %2" : "=v"(r) : "v"(lo), "v"(hi));
    return r;
}

__device__ __forceinline__ float fast_exp2(float x) {
#if __has_builtin(__builtin_amdgcn_exp2f)
    return __builtin_amdgcn_exp2f(x);
#else
    return exp2f(x);
#endif
}

// ---------------------------------------------------------------------------
// W convert: Wb[96][256] = {Wv*log2e, Wk, Wq} bf16. (proven)
// ---------------------------------------------------------------------------
__global__ __launch_bounds__(256) void convw_kernel(
    const float* __restrict__ Wv, const float* __restrict__ Wk,
    const float* __restrict__ Wq, __hip_bfloat16* __restrict__ Wb)
{
    const int idx = blockIdx.x * 256 + threadIdx.x;  // < 24576
    if (idx < 8192)        Wb[idx] = __float2bfloat16(Wv[idx] * LOG2E_F);
    else if (idx < 16384)  Wb[idx] = __float2bfloat16(Wk[idx - 8192]);
    else                   Wb[idx] = __float2bfloat16(Wq[idx - 16384]);
}

// ---------------------------------------------------------------------------
// Projection via MFMA. grid (N/64, B), block 512 (8 waves).
// REVERTED to the round-4/5 PROVEN version (per-lane x loads, in-reg cvt).
// ---------------------------------------------------------------------------
__global__ __launch_bounds__(512) void proj_kernel(
    const __hip_bfloat16* __restrict__ Wb,
    const float* __restrict__ bv, const float* __restrict__ bk,
    const float* __restrict__ bq,
    const float* __restrict__ x,
    __hip_bfloat16* __restrict__ q_t, __hip_bfloat16* __restrict__ k_t,
    __hip_bfloat16* __restrict__ h_n)
{
    __shared__ uint32_t tq[4][16][44];  // [ns][n-local][cr-dword], 176B rows
    __shared__ uint32_t tk[4][16][44];

    const int tid  = threadIdx.x;
    const int lane = tid & 63;
    const int w    = __builtin_amdgcn_readfirstlane(tid >> 6);
    const int ns   = w & 3;
    const int mg   = w >> 2;
    const int b    = blockIdx.y;
    const int n0   = blockIdx.x * 64;
    const int m    = lane & 15;
    const int h4   = lane >> 4;
    const int ncol = n0 + 16 * ns + m;

    // ---- B fragments: x[32s+8h4+e][ncol] -> bf16, 8 K-steps ----
    bf16x8 bfr[8];
    #pragma unroll
    for (int s = 0; s < 8; ++s) {
        const float* xp = x + ((size_t)b * C_ + 32 * s + 8 * h4) * N_ + ncol;
        float xe[8];
        #pragma unroll
        for (int e = 0; e < 8; ++e) xe[e] = xp[(size_t)e * N_];
        uint4 u;
        u.x = cvt_pk_bf16(xe[0], xe[1]);
        u.y = cvt_pk_bf16(xe[2], xe[3]);
        u.z = cvt_pk_bf16(xe[4], xe[5]);
        u.w = cvt_pk_bf16(xe[6], xe[7]);
        bfr[s] = __builtin_bit_cast(bf16x8, u);
    }

    // ---- 3 interleaved MFMA chains (f, g, h), bias as C-init ----
    const int mrow = 16 * mg;
    const float4 b4v = *(const float4*)&bv[mrow + 4 * h4];
    const float4 b4k = *(const float4*)&bk[mrow + 4 * h4];
    const float4 b4q = *(const float4*)&bq[mrow + 4 * h4];
    f32x4 accF = {b4v.x * LOG2E_F, b4v.y * LOG2E_F, b4v.z * LOG2E_F, b4v.w * LOG2E_F};
    f32x4 accG = {b4k.x, b4k.y, b4k.z, b4k.w};
    f32x4 accH = {b4q.x, b4q.y, b4q.z, b4q.w};
    const __hip_bfloat16* wF = Wb + (size_t)(mrow + m) * 256;
    const __hip_bfloat16* wG = wF + (size_t)32 * 256;
    const __hip_bfloat16* wH = wG + (size_t)32 * 256;
    #pragma unroll
    for (int s = 0; s < 8; ++s) {
        const bf16x8 aF = *(const bf16x8*)(wF + 32 * s + 8 * h4);
        const bf16x8 aG = *(const bf16x8*)(wG + 32 * s + 8 * h4);
        const bf16x8 aH = *(const bf16x8*)(wH + 32 * s + 8 * h4);
        accF = __builtin_amdgcn_mfma_f32_16x16x32_bf16(aF, bfr[s], accF, 0, 0, 0);
        accG = __builtin_amdgcn_mfma_f32_16x16x32_bf16(aG, bfr[s], accG, 0, 0, 0);
        accH = __builtin_amdgcn_mfma_f32_16x16x32_bf16(aH, bfr[s], accH, 0, 0, 0);
    }

    // ---- f,g -> LDS transpose; h -> direct store ----
    tq[ns][m][8 * mg + 2 * h4 + 0] = cvt_pk_bf16(accF[0], accF[1]);
    tq[ns][m][8 * mg + 2 * h4 + 1] = cvt_pk_bf16(accF[2], accF[3]);
    tk[ns][m][8 * mg + 2 * h4 + 0] = cvt_pk_bf16(accG[0], accG[1]);
    tk[ns][m][8 * mg + 2 * h4 + 1] = cvt_pk_bf16(accG[2], accG[3]);
    #pragma unroll
    for (int r = 0; r < 4; ++r) {
        const int ch = mrow + 4 * h4 + r;
        h_n[((size_t)b * CR_ + ch) * N_ + ncol] = __float2bfloat16(accH[r]);
    }
    __syncthreads();

    {
        const int sl = w & 3;
        const uint32_t* src = (w < 4) ? &tq[sl][0][0] : &tk[sl][0][0];
        const uint4 val = *(const uint4*)(src + m * 44 + 4 * h4);
        __hip_bfloat16* dst = ((w < 4) ? q_t : k_t) +
            ((size_t)b * N_ + n0 + 16 * sl + m) * CR_ + 8 * h4;
        *(uint4*)dst = val;
    }
}

// ---------------------------------------------------------------------------
// Flash attention, j-split. grid (N/64, B, JS), block 256 (4 waves).
// BYTE-IDENTICAL to round 7: block-cooperative double-buffered LDS staging.
// ---------------------------------------------------------------------------
template <int JS>
__global__ __launch_bounds__(256) void flash_kernel(
    const __hip_bfloat16* __restrict__ q_t,
    const __hip_bfloat16* __restrict__ k_t,
    const __hip_bfloat16* __restrict__ h_n,
    float* __restrict__ ws_acc,   // [B][JS][CR][N]
    float* __restrict__ ws_ml)    // [B][JS][2][N]
{
    constexpr int CHUNK = N_ / JS;
    constexpr int NT    = CHUNK / 64;

    __shared__ __hip_bfloat16 Klds[2][64][40];   // K tile, 80B pitch (b128-aligned)
    __shared__ __hip_bfloat16 Hlds[2][32][72];   // H tile, 144B pitch
    __shared__ __hip_bfloat16 p_lds[4][16][72];  // per-wave P tile (proven)

    const int tid  = threadIdx.x;
    const int lane = tid & 63;
    const int w    = __builtin_amdgcn_readfirstlane(tid >> 6);
    const int b    = blockIdx.y;
    const int js   = blockIdx.z;
    const int i0   = blockIdx.x * 64;
    const int iw   = i0 + w * 16;

    const int m  = lane & 15;
    const int h4 = lane >> 4;

    // staging decomposition
    const int krow = tid >> 2, kseg = tid & 3;   // K: 64 rows x 4 x 16B
    const int hrow = tid >> 3, hseg = tid & 7;   // H: 32 rows x 8 x 16B

    const bf16x8 qa = *(const bf16x8*)(q_t + ((size_t)b * N_ + iw + m) * CR_ + 8 * h4);

    f32x4 acc0 = {0.f, 0.f, 0.f, 0.f};
    f32x4 acc1 = {0.f, 0.f, 0.f, 0.f};
    float m_run[4]  = {-INFINITY, -INFINITY, -INFINITY, -INFINITY};
    float l_part[4] = {0.f, 0.f, 0.f, 0.f};

    const __hip_bfloat16* kbase = k_t + ((size_t)b * N_ + (size_t)js * CHUNK) * CR_;
    const __hip_bfloat16* hbase = h_n + (size_t)b * CR_ * N_ + (size_t)js * CHUNK;
    const f32x4 z = {0.f, 0.f, 0.f, 0.f};

    auto stage_load = [&](uint4& kr, uint4& hr, int jt) {
        kr = *(const uint4*)(kbase + (size_t)(jt * 64 + krow) * CR_ + kseg * 8);
        hr = *(const uint4*)(hbase + (size_t)hrow * N_ + jt * 64 + hseg * 8);
    };
    auto stage_write = [&](int buf, const uint4& kr, const uint4& hr) {
        *(uint4*)&Klds[buf][krow][kseg * 8] = kr;
        *(uint4*)&Hlds[buf][hrow][hseg * 8] = hr;
    };

    auto compute = [&](int buf) {
        bf16x8 K0[4], H0[4];
        #pragma unroll
        for (int t = 0; t < 4; ++t)
            K0[t] = *(const bf16x8*)&Klds[buf][4 * m + t][8 * h4];
        H0[0] = *(const bf16x8*)&Hlds[buf][m][8 * h4];
        H0[1] = *(const bf16x8*)&Hlds[buf][16 + m][8 * h4];
        H0[2] = *(const bf16x8*)&Hlds[buf][m][32 + 8 * h4];
        H0[3] = *(const bf16x8*)&Hlds[buf][16 + m][32 + 8 * h4];

        f32x4 s[4];
        #pragma unroll
        for (int t = 0; t < 4; ++t)
            s[t] = __builtin_amdgcn_mfma_f32_16x16x32_bf16(qa, K0[t], z, 0, 0, 0);

        float mt[4];
        #pragma unroll
        for (int r = 0; r < 4; ++r)
            mt[r] = fmaxf(fmaxf(s[0][r], s[1][r]), fmaxf(s[2][r], s[3][r]));
        const float dmax = fmaxf(fmaxf(mt[0] - m_run[0], mt[1] - m_run[1]),
                                 fmaxf(mt[2] - m_run[2], mt[3] - m_run[3]));
        if (__any(dmax > 8.0f)) {
            #pragma unroll
            for (int r = 0; r < 4; ++r) {
                float v = mt[r];
                v = fmaxf(v, __shfl_xor(v, 1));
                v = fmaxf(v, __shfl_xor(v, 2));
                v = fmaxf(v, __shfl_xor(v, 4));
                v = fmaxf(v, __shfl_xor(v, 8));
                const float mn = fmaxf(m_run[r], v);
                const float sc = fast_exp2(m_run[r] - mn);
                m_run[r] = mn;
                l_part[r] *= sc;
                acc0[r] *= sc;
                acc1[r] *= sc;
            }
        }

        #pragma unroll
        for (int r = 0; r < 4; ++r) {
            const float p0 = fast_exp2(s[0][r] - m_run[r]);
            const float p1 = fast_exp2(s[1][r] - m_run[r]);
            const float p2 = fast_exp2(s[2][r] - m_run[r]);
            const float p3 = fast_exp2(s[3][r] - m_run[r]);
            l_part[r] += (p0 + p1) + (p2 + p3);
            uint2 v;
            v.x = cvt_pk_bf16(p0, p1);
            v.y = cvt_pk_bf16(p2, p3);
            *(uint2*)&p_lds[w][4 * h4 + r][4 * m] = v;
        }

        const bf16x8 pa0 = *(const bf16x8*)&p_lds[w][m][8 * h4];
        const bf16x8 pa1 = *(const bf16x8*)&p_lds[w][m][32 + 8 * h4];

        acc0 = __builtin_amdgcn_mfma_f32_16x16x32_bf16(pa0, H0[0], acc0, 0, 0, 0);
        acc0 = __builtin_amdgcn_mfma_f32_16x16x32_bf16(pa1, H0[2], acc0, 0, 0, 0);
        acc1 = __builtin_amdgcn_mfma_f32_16x16x32_bf16(pa0, H0[1], acc1, 0, 0, 0);
        acc1 = __builtin_amdgcn_mfma_f32_16x16x32_bf16(pa1, H0[3], acc1, 0, 0, 0);
    };

    // prologue: stage tile 0
    uint4 kreg, hreg;
    stage_load(kreg, hreg, 0);
    stage_write(0, kreg, hreg);
    __syncthreads();

    #pragma unroll 1
    for (int jt = 0; jt < NT; ++jt) {
        const int cur = jt & 1;
        const int jn  = (jt + 1 < NT) ? jt + 1 : jt;  // clamped (no OOB)
        stage_load(kreg, hreg, jn);    // issued early; latency hides under compute
        compute(cur);
        __syncthreads();               // all waves done reading buf[cur^1] prev iter
        stage_write(cur ^ 1, kreg, hreg);
        __syncthreads();               // buf[cur^1] ready for next iter
    }

    // ---- epilogue (proven) ----
    float l_row[4];
    #pragma unroll
    for (int r = 0; r < 4; ++r) {
        float v = l_part[r];
        v += __shfl_xor(v, 1);
        v += __shfl_xor(v, 2);
        v += __shfl_xor(v, 4);
        v += __shfl_xor(v, 8);
        l_row[r] = v;
    }
    float* wa = ws_acc + (((size_t)b * JS + js) * CR_ + m) * N_ + iw + 4 * h4;
    *(f32x4*)wa = acc0;
    *(f32x4*)(wa + (size_t)16 * N_) = acc1;
    if (m == 0) {
        const size_t base = ((size_t)b * JS + js) * 2 * N_ + iw + 4 * h4;
        #pragma unroll
        for (int r = 0; r < 4; ++r) {
            ws_ml[base + r]      = m_run[r];
            ws_ml[base + N_ + r] = l_row[r];
        }
    }
}

// ---------------------------------------------------------------------------
// Combine (byte-identical to round 5 — proven). grid (N/64, B), block 512.
// ---------------------------------------------------------------------------
template <int JS>
__global__ __launch_bounds__(512) void combine_kernel(
    const float* __restrict__ ws_acc, const float* __restrict__ ws_ml,
    const float* __restrict__ x,
    const float* __restrict__ Wo, const float* __restrict__ bo,
    const float* __restrict__ gamma_p,
    float* __restrict__ y)
{
    __shared__ float wo_lds[256][32];   // 32 KB
    __shared__ float vals_lds[32][64];  // 8 KB

    const int tid = threadIdx.x;
    const int il  = tid & 63;
    const int grp = __builtin_amdgcn_readfirstlane(tid >> 6);  // 0..7
    const int b   = blockIdx.y;
    const int i0  = blockIdx.x * 64;
    const int i   = i0 + il;

    #pragma unroll
    for (int k = 0; k < 4; ++k) {
        const int i4 = (tid + 512 * k) * 4;  // 0..32764
        *(float4*)&wo_lds[i4 >> 5][i4 & 31] = *(const float4*)&Wo[i4];
    }

    {
        float mC[JS], lC[JS];
        #pragma unroll
        for (int c = 0; c < JS; ++c) {
            const size_t base = ((size_t)b * JS + c) * 2 * N_;
            mC[c] = ws_ml[base + i];
            lC[c] = ws_ml[base + N_ + i];
        }
        float mf = mC[0];
        #pragma unroll
        for (int c = 1; c < JS; ++c) mf = fmaxf(mf, mC[c]);
        float wgt[JS];
        float denom = 0.f;
        #pragma unroll
        for (int c = 0; c < JS; ++c) {
            wgt[c] = fast_exp2(mC[c] - mf);
            denom += lC[c] * wgt[c];
        }
        const float inv = 1.0f / denom;

        #pragma unroll
        for (int k = 0; k < 4; ++k) {
            const int cr = 4 * grp + k;
            float a = 0.f;
            #pragma unroll
            for (int c = 0; c < JS; ++c)
                a += ws_acc[(((size_t)b * JS + c) * CR_ + cr) * N_ + i] * wgt[c];
            vals_lds[cr][il] = a * inv;
        }
    }
    __syncthreads();

    float vals[32];
    #pragma unroll
    for (int cr = 0; cr < 32; ++cr) vals[cr] = vals_lds[cr][il];

    const float gmv = gamma_p[0];
    const float* xb = x + (size_t)b * C_ * N_ + i;
    float* yb = y + (size_t)b * C_ * N_ + i;
    for (int k = 0; k < 32; ++k) {
        const int co = grp * 32 + k;
        const float* wr = &wo_lds[co][0];
        float a = bo[co];
        #pragma unroll
        for (int q = 0; q < 8; ++q) {
            const float4 w4 = *(const float4*)&wr[4 * q];
            a += w4.x * vals[4 * q] + w4.y * vals[4 * q + 1] +
                 w4.z * vals[4 * q + 2] + w4.w * vals[4 * q + 3];
        }
        yb[(size_t)co * N_] = gmv * a + xb[(size_t)co * N_];
    }
}

extern "C" void kernel_launch(void* const* d_in, const int* in_sizes, int n_in,
                              void* d_out, int out_size, void* d_ws, size_t ws_size,
                              hipStream_t stream) {
    (void)in_sizes; (void)n_in; (void)out_size;
    const float* x  = (const float*)d_in[0];
    const float* Wv = (const float*)d_in[1];
    const float* bv = (const float*)d_in[2];
    const float* Wk = (const float*)d_in[3];
    const float* bk = (const float*)d_in[4];
    const float* Wq = (const float*)d_in[5];
    const float* bq = (const float*)d_in[6];
    const float* Wo = (const float*)d_in[7];
    const float* bo = (const float*)d_in[8];
    const float* gm = (const float*)d_in[9];
    float* y = (float*)d_out;

    __hip_bfloat16* q_t = (__hip_bfloat16*)d_ws;          // f*log2e, [B][N][CR]
    __hip_bfloat16* k_t = q_t + (size_t)B_ * N_ * CR_;    // g,       [B][N][CR]
    __hip_bfloat16* h_n = k_t + (size_t)B_ * N_ * CR_;    // h,       [B][CR][N]
    __hip_bfloat16* Wb  = h_n + (size_t)B_ * CR_ * N_;    // [96][256] bf16
    float* ws_acc = (float*)(Wb + (size_t)96 * 256);
    const size_t base_off = (size_t)((char*)ws_acc - (char*)d_ws);
    const size_t need8 = base_off + (size_t)B_ * 8 * CR_ * N_ * 4
                                  + (size_t)B_ * 8 * 2 * N_ * 4;

    convw_kernel<<<96, 256, 0, stream>>>(Wv, Wk, Wq, Wb);
    proj_kernel<<<dim3(N_ / 64, B_), 512, 0, stream>>>(Wb, bv, bk, bq, x,
                                                       q_t, k_t, h_n);

    if (ws_size >= need8) {
        float* ws_ml = ws_acc + (size_t)B_ * 8 * CR_ * N_;
        flash_kernel<8><<<dim3(N_ / 64, B_, 8), 256, 0, stream>>>(q_t, k_t, h_n,
                                                                  ws_acc, ws_ml);
        combine_kernel<8><<<dim3(N_ / 64, B_), 512, 0, stream>>>(ws_acc, ws_ml, x,
                                                                 Wo, bo, gm, y);
    } else {
        float* ws_ml = ws_acc + (size_t)B_ * 4 * CR_ * N_;
        flash_kernel<4><<<dim3(N_ / 64, B_, 4), 256, 0, stream>>>(q_t, k_t, h_n,
                                                                  ws_acc, ws_ml);
        combine_kernel<4><<<dim3(N_ / 64, B_), 512, 0, stream>>>(ws_acc, ws_ml, x,
                                                                 Wo, bo, gm, y);
    }
}

// Round 10
// 134.209 us; speedup vs baseline: 1.8228x; 1.0414x over previous
//
#include <hip/hip_runtime.h>
#include <hip/hip_bf16.h>
#include <stdint.h>

#define B_ 4
#define C_ 256
#define N_ 4096
#define CR_ 32
#define LOG2E_F 1.44269504088896340736f

typedef __attribute__((ext_vector_type(8))) short bf16x8;
typedef __attribute__((ext_vector_type(4))) float f32x4;

__device__ __forceinline__ uint32_t cvt_pk_bf16(float lo, float hi) {
    uint32_t r;
    asm("v_cvt_pk_bf16_f32 %0, %1, %2" : "=v"(r) : "v"(lo), "v"(hi));
    return r;
}

__device__ __forceinline__ float fast_exp2(float x) {
#if __has_builtin(__builtin_amdgcn_exp2f)
    return __builtin_amdgcn_exp2f(x);
#else
    return exp2f(x);
#endif
}

// ---------------------------------------------------------------------------
// W convert: Wb[96][256] = {Wv*log2e, Wk, Wq} bf16. (proven)
// ---------------------------------------------------------------------------
__global__ __launch_bounds__(256) void convw_kernel(
    const float* __restrict__ Wv, const float* __restrict__ Wk,
    const float* __restrict__ Wq, __hip_bfloat16* __restrict__ Wb)
{
    const int idx = blockIdx.x * 256 + threadIdx.x;  // < 24576
    if (idx < 8192)        Wb[idx] = __float2bfloat16(Wv[idx] * LOG2E_F);
    else if (idx < 16384)  Wb[idx] = __float2bfloat16(Wk[idx - 8192]);
    else                   Wb[idx] = __float2bfloat16(Wq[idx - 16384]);
}

// ---------------------------------------------------------------------------
// Projection via MFMA, z-split over the 3 projections. grid (N/64, B, 3),
// block 512 (8 waves). z: 0=F(->q_t), 1=G(->k_t), 2=H(->h_n).
// x loads / fragment math byte-level identical to the r8-PROVEN pattern;
// each block runs ONE MFMA chain (its projection) instead of three.
// 768 blocks -> 3 blocks/CU -> 3x latency hiding on the strided x loads.
// ---------------------------------------------------------------------------
__global__ __launch_bounds__(512) void proj_kernel(
    const __hip_bfloat16* __restrict__ Wb,
    const float* __restrict__ bv, const float* __restrict__ bk,
    const float* __restrict__ bq,
    const float* __restrict__ x,
    __hip_bfloat16* __restrict__ q_t, __hip_bfloat16* __restrict__ k_t,
    __hip_bfloat16* __restrict__ h_n)
{
    __shared__ uint32_t t[4][16][44];  // [ns][n-local][cr-dword] (z=0/1 only)

    const int tid  = threadIdx.x;
    const int lane = tid & 63;
    const int w    = __builtin_amdgcn_readfirstlane(tid >> 6);
    const int ns   = w & 3;
    const int mg   = w >> 2;
    const int b    = blockIdx.y;
    const int z    = blockIdx.z;       // 0=F, 1=G, 2=H
    const int n0   = blockIdx.x * 64;
    const int m    = lane & 15;
    const int h4   = lane >> 4;
    const int ncol = n0 + 16 * ns + m;

    // ---- B fragments: x[32s+8h4+e][ncol] -> bf16, 8 K-steps (r8-proven) ----
    bf16x8 bfr[8];
    #pragma unroll
    for (int s = 0; s < 8; ++s) {
        const float* xp = x + ((size_t)b * C_ + 32 * s + 8 * h4) * N_ + ncol;
        float xe[8];
        #pragma unroll
        for (int e = 0; e < 8; ++e) xe[e] = xp[(size_t)e * N_];
        uint4 u;
        u.x = cvt_pk_bf16(xe[0], xe[1]);
        u.y = cvt_pk_bf16(xe[2], xe[3]);
        u.z = cvt_pk_bf16(xe[4], xe[5]);
        u.w = cvt_pk_bf16(xe[6], xe[7]);
        bfr[s] = __builtin_bit_cast(bf16x8, u);
    }

    // ---- single MFMA chain for this block's projection, bias as C-init ----
    const int mrow = 16 * mg;
    const float* bias = (z == 0) ? bv : (z == 1) ? bk : bq;
    const float bscale = (z == 0) ? LOG2E_F : 1.0f;
    const float4 b4 = *(const float4*)&bias[mrow + 4 * h4];
    f32x4 acc = {b4.x * bscale, b4.y * bscale, b4.z * bscale, b4.w * bscale};
    const __hip_bfloat16* wP = Wb + ((size_t)z * 32 + mrow + m) * 256;
    #pragma unroll
    for (int s = 0; s < 8; ++s) {
        const bf16x8 aP = *(const bf16x8*)(wP + 32 * s + 8 * h4);
        acc = __builtin_amdgcn_mfma_f32_16x16x32_bf16(aP, bfr[s], acc, 0, 0, 0);
    }

    if (z == 2) {
        // ---- H: direct store (r8-proven path) ----
        #pragma unroll
        for (int r = 0; r < 4; ++r) {
            const int ch = mrow + 4 * h4 + r;
            h_n[((size_t)b * CR_ + ch) * N_ + ncol] = __float2bfloat16(acc[r]);
        }
    } else {
        // ---- F/G: LDS transpose + cooperative coalesced store (r8-proven) ----
        t[ns][m][8 * mg + 2 * h4 + 0] = cvt_pk_bf16(acc[0], acc[1]);
        t[ns][m][8 * mg + 2 * h4 + 1] = cvt_pk_bf16(acc[2], acc[3]);
        __syncthreads();
        if (w < 4) {
            const uint4 val = *(const uint4*)(&t[w][0][0] + m * 44 + 4 * h4);
            __hip_bfloat16* dst = ((z == 0) ? q_t : k_t) +
                ((size_t)b * N_ + n0 + 16 * w + m) * CR_ + 8 * h4;
            *(uint4*)dst = val;
        }
    }
}

// ---------------------------------------------------------------------------
// Flash attention, j-split. grid (N/64, B, JS), block 256 (4 waves).
// BYTE-IDENTICAL to round 8 (proven): block-cooperative double-buffered
// LDS staging.
// ---------------------------------------------------------------------------
template <int JS>
__global__ __launch_bounds__(256) void flash_kernel(
    const __hip_bfloat16* __restrict__ q_t,
    const __hip_bfloat16* __restrict__ k_t,
    const __hip_bfloat16* __restrict__ h_n,
    float* __restrict__ ws_acc,   // [B][JS][CR][N]
    float* __restrict__ ws_ml)    // [B][JS][2][N]
{
    constexpr int CHUNK = N_ / JS;
    constexpr int NT    = CHUNK / 64;

    __shared__ __hip_bfloat16 Klds[2][64][40];   // K tile, 80B pitch (b128-aligned)
    __shared__ __hip_bfloat16 Hlds[2][32][72];   // H tile, 144B pitch
    __shared__ __hip_bfloat16 p_lds[4][16][72];  // per-wave P tile (proven)

    const int tid  = threadIdx.x;
    const int lane = tid & 63;
    const int w    = __builtin_amdgcn_readfirstlane(tid >> 6);
    const int b    = blockIdx.y;
    const int js   = blockIdx.z;
    const int i0   = blockIdx.x * 64;
    const int iw   = i0 + w * 16;

    const int m  = lane & 15;
    const int h4 = lane >> 4;

    // staging decomposition
    const int krow = tid >> 2, kseg = tid & 3;   // K: 64 rows x 4 x 16B
    const int hrow = tid >> 3, hseg = tid & 7;   // H: 32 rows x 8 x 16B

    const bf16x8 qa = *(const bf16x8*)(q_t + ((size_t)b * N_ + iw + m) * CR_ + 8 * h4);

    f32x4 acc0 = {0.f, 0.f, 0.f, 0.f};
    f32x4 acc1 = {0.f, 0.f, 0.f, 0.f};
    float m_run[4]  = {-INFINITY, -INFINITY, -INFINITY, -INFINITY};
    float l_part[4] = {0.f, 0.f, 0.f, 0.f};

    const __hip_bfloat16* kbase = k_t + ((size_t)b * N_ + (size_t)js * CHUNK) * CR_;
    const __hip_bfloat16* hbase = h_n + (size_t)b * CR_ * N_ + (size_t)js * CHUNK;
    const f32x4 z = {0.f, 0.f, 0.f, 0.f};

    auto stage_load = [&](uint4& kr, uint4& hr, int jt) {
        kr = *(const uint4*)(kbase + (size_t)(jt * 64 + krow) * CR_ + kseg * 8);
        hr = *(const uint4*)(hbase + (size_t)hrow * N_ + jt * 64 + hseg * 8);
    };
    auto stage_write = [&](int buf, const uint4& kr, const uint4& hr) {
        *(uint4*)&Klds[buf][krow][kseg * 8] = kr;
        *(uint4*)&Hlds[buf][hrow][hseg * 8] = hr;
    };

    auto compute = [&](int buf) {
        bf16x8 K0[4], H0[4];
        #pragma unroll
        for (int t = 0; t < 4; ++t)
            K0[t] = *(const bf16x8*)&Klds[buf][4 * m + t][8 * h4];
        H0[0] = *(const bf16x8*)&Hlds[buf][m][8 * h4];
        H0[1] = *(const bf16x8*)&Hlds[buf][16 + m][8 * h4];
        H0[2] = *(const bf16x8*)&Hlds[buf][m][32 + 8 * h4];
        H0[3] = *(const bf16x8*)&Hlds[buf][16 + m][32 + 8 * h4];

        f32x4 s[4];
        #pragma unroll
        for (int t = 0; t < 4; ++t)
            s[t] = __builtin_amdgcn_mfma_f32_16x16x32_bf16(qa, K0[t], z, 0, 0, 0);

        float mt[4];
        #pragma unroll
        for (int r = 0; r < 4; ++r)
            mt[r] = fmaxf(fmaxf(s[0][r], s[1][r]), fmaxf(s[2][r], s[3][r]));
        const float dmax = fmaxf(fmaxf(mt[0] - m_run[0], mt[1] - m_run[1]),
                                 fmaxf(mt[2] - m_run[2], mt[3] - m_run[3]));
        if (__any(dmax > 8.0f)) {
            #pragma unroll
            for (int r = 0; r < 4; ++r) {
                float v = mt[r];
                v = fmaxf(v, __shfl_xor(v, 1));
                v = fmaxf(v, __shfl_xor(v, 2));
                v = fmaxf(v, __shfl_xor(v, 4));
                v = fmaxf(v, __shfl_xor(v, 8));
                const float mn = fmaxf(m_run[r], v);
                const float sc = fast_exp2(m_run[r] - mn);
                m_run[r] = mn;
                l_part[r] *= sc;
                acc0[r] *= sc;
                acc1[r] *= sc;
            }
        }

        #pragma unroll
        for (int r = 0; r < 4; ++r) {
            const float p0 = fast_exp2(s[0][r] - m_run[r]);
            const float p1 = fast_exp2(s[1][r] - m_run[r]);
            const float p2 = fast_exp2(s[2][r] - m_run[r]);
            const float p3 = fast_exp2(s[3][r] - m_run[r]);
            l_part[r] += (p0 + p1) + (p2 + p3);
            uint2 v;
            v.x = cvt_pk_bf16(p0, p1);
            v.y = cvt_pk_bf16(p2, p3);
            *(uint2*)&p_lds[w][4 * h4 + r][4 * m] = v;
        }

        const bf16x8 pa0 = *(const bf16x8*)&p_lds[w][m][8 * h4];
        const bf16x8 pa1 = *(const bf16x8*)&p_lds[w][m][32 + 8 * h4];

        acc0 = __builtin_amdgcn_mfma_f32_16x16x32_bf16(pa0, H0[0], acc0, 0, 0, 0);
        acc0 = __builtin_amdgcn_mfma_f32_16x16x32_bf16(pa1, H0[2], acc0, 0, 0, 0);
        acc1 = __builtin_amdgcn_mfma_f32_16x16x32_bf16(pa0, H0[1], acc1, 0, 0, 0);
        acc1 = __builtin_amdgcn_mfma_f32_16x16x32_bf16(pa1, H0[3], acc1, 0, 0, 0);
    };

    // prologue: stage tile 0
    uint4 kreg, hreg;
    stage_load(kreg, hreg, 0);
    stage_write(0, kreg, hreg);
    __syncthreads();

    #pragma unroll 1
    for (int jt = 0; jt < NT; ++jt) {
        const int cur = jt & 1;
        const int jn  = (jt + 1 < NT) ? jt + 1 : jt;  // clamped (no OOB)
        stage_load(kreg, hreg, jn);    // issued early; latency hides under compute
        compute(cur);
        __syncthreads();               // all waves done reading buf[cur^1] prev iter
        stage_write(cur ^ 1, kreg, hreg);
        __syncthreads();               // buf[cur^1] ready for next iter
    }

    // ---- epilogue (proven) ----
    float l_row[4];
    #pragma unroll
    for (int r = 0; r < 4; ++r) {
        float v = l_part[r];
        v += __shfl_xor(v, 1);
        v += __shfl_xor(v, 2);
        v += __shfl_xor(v, 4);
        v += __shfl_xor(v, 8);
        l_row[r] = v;
    }
    float* wa = ws_acc + (((size_t)b * JS + js) * CR_ + m) * N_ + iw + 4 * h4;
    *(f32x4*)wa = acc0;
    *(f32x4*)(wa + (size_t)16 * N_) = acc1;
    if (m == 0) {
        const size_t base = ((size_t)b * JS + js) * 2 * N_ + iw + 4 * h4;
        #pragma unroll
        for (int r = 0; r < 4; ++r) {
            ws_ml[base + r]      = m_run[r];
            ws_ml[base + N_ + r] = l_row[r];
        }
    }
}

// ---------------------------------------------------------------------------
// Combine, z-split over output channels. grid (N/64, B, 2), block 512.
// Phase-1 state-merge logic byte-identical to the proven version (computed
// redundantly per half); phase 2 covers 128 channels/block with a 16 KB
// Wo half staged in LDS. 512 blocks -> 2 blocks/CU.
// ---------------------------------------------------------------------------
template <int JS>
__global__ __launch_bounds__(512) void combine_kernel(
    const float* __restrict__ ws_acc, const float* __restrict__ ws_ml,
    const float* __restrict__ x,
    const float* __restrict__ Wo, const float* __restrict__ bo,
    const float* __restrict__ gamma_p,
    float* __restrict__ y)
{
    __shared__ float wo_lds[128][32];   // 16 KB (this block's channel half)
    __shared__ float vals_lds[32][64];  // 8 KB

    const int tid = threadIdx.x;
    const int il  = tid & 63;
    const int grp = __builtin_amdgcn_readfirstlane(tid >> 6);  // 0..7
    const int b   = blockIdx.y;
    const int z   = blockIdx.z;        // channel half: co in [z*128, z*128+128)
    const int i0  = blockIdx.x * 64;
    const int i   = i0 + il;

    // ---- stage this half of Wo (coalesced float4) ----
    #pragma unroll
    for (int k = 0; k < 2; ++k) {
        const int i4 = (tid + 512 * k) * 4;  // 0..4092 of 4096 dwords
        *(float4*)&wo_lds[i4 >> 5][i4 & 31] =
            *(const float4*)&Wo[(size_t)z * 4096 + i4];
    }

    // ---- phase 1: softmax-state combine (proven scalar logic) ----
    {
        float mC[JS], lC[JS];
        #pragma unroll
        for (int c = 0; c < JS; ++c) {
            const size_t base = ((size_t)b * JS + c) * 2 * N_;
            mC[c] = ws_ml[base + i];
            lC[c] = ws_ml[base + N_ + i];
        }
        float mf = mC[0];
        #pragma unroll
        for (int c = 1; c < JS; ++c) mf = fmaxf(mf, mC[c]);
        float wgt[JS];
        float denom = 0.f;
        #pragma unroll
        for (int c = 0; c < JS; ++c) {
            wgt[c] = fast_exp2(mC[c] - mf);
            denom += lC[c] * wgt[c];
        }
        const float inv = 1.0f / denom;

        #pragma unroll
        for (int k = 0; k < 4; ++k) {
            const int cr = 4 * grp + k;
            float a = 0.f;
            #pragma unroll
            for (int c = 0; c < JS; ++c)
                a += ws_acc[(((size_t)b * JS + c) * CR_ + cr) * N_ + i] * wgt[c];
            vals_lds[cr][il] = a * inv;
        }
    }
    __syncthreads();

    float vals[32];
    #pragma unroll
    for (int cr = 0; cr < 32; ++cr) vals[cr] = vals_lds[cr][il];

    // ---- phase 2: 16 channels per wave-group, Wo from LDS ----
    const float gmv = gamma_p[0];
    const float* xb = x + (size_t)b * C_ * N_ + i;
    float* yb = y + (size_t)b * C_ * N_ + i;
    for (int k = 0; k < 16; ++k) {
        const int col = grp * 16 + k;        // 0..127 within half
        const int co  = z * 128 + col;
        const float* wr = &wo_lds[col][0];
        float a = bo[co];
        #pragma unroll
        for (int q = 0; q < 8; ++q) {
            const float4 w4 = *(const float4*)&wr[4 * q];
            a += w4.x * vals[4 * q] + w4.y * vals[4 * q + 1] +
                 w4.z * vals[4 * q + 2] + w4.w * vals[4 * q + 3];
        }
        yb[(size_t)co * N_] = gmv * a + xb[(size_t)co * N_];
    }
}

extern "C" void kernel_launch(void* const* d_in, const int* in_sizes, int n_in,
                              void* d_out, int out_size, void* d_ws, size_t ws_size,
                              hipStream_t stream) {
    (void)in_sizes; (void)n_in; (void)out_size;
    const float* x  = (const float*)d_in[0];
    const float* Wv = (const float*)d_in[1];
    const float* bv = (const float*)d_in[2];
    const float* Wk = (const float*)d_in[3];
    const float* bk = (const float*)d_in[4];
    const float* Wq = (const float*)d_in[5];
    const float* bq = (const float*)d_in[6];
    const float* Wo = (const float*)d_in[7];
    const float* bo = (const float*)d_in[8];
    const float* gm = (const float*)d_in[9];
    float* y = (float*)d_out;

    __hip_bfloat16* q_t = (__hip_bfloat16*)d_ws;          // f*log2e, [B][N][CR]
    __hip_bfloat16* k_t = q_t + (size_t)B_ * N_ * CR_;    // g,       [B][N][CR]
    __hip_bfloat16* h_n = k_t + (size_t)B_ * N_ * CR_;    // h,       [B][CR][N]
    __hip_bfloat16* Wb  = h_n + (size_t)B_ * CR_ * N_;    // [96][256] bf16
    float* ws_acc = (float*)(Wb + (size_t)96 * 256);
    const size_t base_off = (size_t)((char*)ws_acc - (char*)d_ws);
    const size_t need8 = base_off + (size_t)B_ * 8 * CR_ * N_ * 4
                                  + (size_t)B_ * 8 * 2 * N_ * 4;

    convw_kernel<<<96, 256, 0, stream>>>(Wv, Wk, Wq, Wb);
    proj_kernel<<<dim3(N_ / 64, B_, 3), 512, 0, stream>>>(Wb, bv, bk, bq, x,
                                                          q_t, k_t, h_n);

    if (ws_size >= need8) {
        float* ws_ml = ws_acc + (size_t)B_ * 8 * CR_ * N_;
        flash_kernel<8><<<dim3(N_ / 64, B_, 8), 256, 0, stream>>>(q_t, k_t, h_n,
                                                                  ws_acc, ws_ml);
        combine_kernel<8><<<dim3(N_ / 64, B_, 2), 512, 0, stream>>>(ws_acc, ws_ml, x,
                                                                    Wo, bo, gm, y);
    } else {
        float* ws_ml = ws_acc + (size_t)B_ * 4 * CR_ * N_;
        flash_kernel<4><<<dim3(N_ / 64, B_, 4), 256, 0, stream>>>(q_t, k_t, h_n,
                                                                  ws_acc, ws_ml);
        combine_kernel<4><<<dim3(N_ / 64, B_, 2), 512, 0, stream>>>(ws_acc, ws_ml, x,
                                                                    Wo, bo, gm, y);
    }
}